// Round 8
// baseline (851.796 us; speedup 1.0000x reference)
//
#include <hip/hip_runtime.h>

#define NH 4
#define ND 16
#define HD 64
#define IN_DIM 128
#define NEG_SLOPE 0.2f
#define BN 128          // dst nodes per bucket
#define NBMAX 1024      // max buckets (n <= 131072)
#define CHUNK 8192      // edges per multisplit block

typedef short bf8 __attribute__((ext_vector_type(8)));   // 8 bf16 in 4 VGPRs
typedef float f4  __attribute__((ext_vector_type(4)));

__device__ inline unsigned short f2bf(float f) {   // RNE fp32 -> bf16
  unsigned u = __float_as_uint(f);
  u += 0x7FFFu + ((u >> 16) & 1u);
  return (unsigned short)(u >> 16);
}

// ---- K1: feat(bf16) = x @ fc_W via MFMA, + el/er per node ----
__global__ __launch_bounds__(256) void k1_mfma(
    const float* __restrict__ x, const float* __restrict__ fcW,
    const float* __restrict__ attn_l, const float* __restrict__ attn_r,
    unsigned short* __restrict__ featb, float4* __restrict__ el4, float4* __restrict__ er4,
    int n)
{
  __shared__ unsigned short wt[HD][IN_DIM + 8];   // W^T bf16, padded
  for (int idx = threadIdx.x; idx < IN_DIM * HD; idx += 256) {
    int k = idx >> 6, j = idx & 63;
    wt[j][k] = f2bf(fcW[idx]);
  }
  __syncthreads();

  const int w  = threadIdx.x >> 6;    // wave 0..3
  const int l  = threadIdx.x & 63;
  const int lr = l & 15;
  const int lg = l >> 4;
  const int rowbase = blockIdx.x * 64 + w * 16;

  int arow = rowbase + lr;
  if (arow >= n) arow = n - 1;                     // clamp; stores predicated
  const float* xp = x + (size_t)arow * IN_DIM + lg * 8;

  f4 acc[4] = {};                                  // one per n-tile (= head)
#pragma unroll
  for (int kc = 0; kc < 4; ++kc) {
    float4 a0 = *(const float4*)(xp + kc * 32);
    float4 a1 = *(const float4*)(xp + kc * 32 + 4);
    bf8 af;
    af[0] = (short)f2bf(a0.x); af[1] = (short)f2bf(a0.y);
    af[2] = (short)f2bf(a0.z); af[3] = (short)f2bf(a0.w);
    af[4] = (short)f2bf(a1.x); af[5] = (short)f2bf(a1.y);
    af[6] = (short)f2bf(a1.z); af[7] = (short)f2bf(a1.w);
#pragma unroll
    for (int nt = 0; nt < 4; ++nt) {
      bf8 bfr = *(const bf8*)&wt[nt * 16 + lr][kc * 32 + lg * 8];
      acc[nt] = __builtin_amdgcn_mfma_f32_16x16x32_bf16(af, bfr, acc[nt], 0, 0, 0);
    }
  }

  float al[NH], ar[NH];
#pragma unroll
  for (int h = 0; h < NH; ++h) { al[h] = attn_l[h * 16 + lr]; ar[h] = attn_r[h * 16 + lr]; }

#pragma unroll
  for (int r = 0; r < 4; ++r) {
    int grow = rowbase + lg * 4 + r;
    bool ok = grow < n;
    if (ok) {
#pragma unroll
      for (int nt = 0; nt < 4; ++nt)
        featb[(size_t)grow * HD + nt * 16 + lr] = f2bf(acc[nt][r]);
    }
    float pl[NH], pr[NH];
#pragma unroll
    for (int h = 0; h < NH; ++h) { pl[h] = acc[h][r] * al[h]; pr[h] = acc[h][r] * ar[h]; }
#pragma unroll
    for (int off = 1; off < 16; off <<= 1) {
#pragma unroll
      for (int h = 0; h < NH; ++h) {
        pl[h] += __shfl_xor(pl[h], off);
        pr[h] += __shfl_xor(pr[h], off);
      }
    }
    if (ok && lr == 0) {
      el4[grow] = make_float4(pl[0], pl[1], pl[2], pl[3]);
      er4[grow] = make_float4(pr[0], pr[1], pr[2], pr[3]);
    }
  }
}

// ---- P0: bucket counts (bin = dst>>7), LDS histogram ----
__global__ __launch_bounds__(256) void k_bincnt(
    const int* __restrict__ dst, int* __restrict__ bincnt, int ne, int nb)
{
  __shared__ int lc[NBMAX];
  for (int i = threadIdx.x; i < nb; i += 256) lc[i] = 0;
  __syncthreads();
  for (int e = blockIdx.x * 256 + threadIdx.x; e < ne; e += gridDim.x * 256)
    atomicAdd(&lc[dst[e] >> 7], 1);
  __syncthreads();
  for (int i = threadIdx.x; i < nb; i += 256)
    if (lc[i]) atomicAdd(&bincnt[i], lc[i]);
}

// ---- P1: scan bucket counts -> bbase/bnext (single block) + tiny ee fused ----
__global__ __launch_bounds__(256) void k_scan_ee(
    const int* __restrict__ bincnt, int* __restrict__ bbase, int* __restrict__ bnext,
    int nb, int ne,
    const float* __restrict__ edge_emb, const float* __restrict__ fc_e_W,
    const float* __restrict__ attn_e, float* __restrict__ ee)
{
  __shared__ int wsm[4], wbs[4];
  __shared__ float sef[8][128];
  const int t = threadIdx.x;
  int c[4], s = 0;
#pragma unroll
  for (int j = 0; j < 4; ++j) { int b = 4 * t + j; c[j] = (b < nb) ? bincnt[b] : 0; s += c[j]; }
  const int lane = t & 63, wv = t >> 6;
  int inc = s;
#pragma unroll
  for (int off = 1; off < 64; off <<= 1) {
    int v = __shfl_up(inc, off);
    if (lane >= off) inc += v;
  }
  if (lane == 63) wsm[wv] = inc;
  if (t < 128) {
    for (int r = 0; r < 8; ++r) {
      float acc = 0.f;
#pragma unroll
      for (int k = 0; k < 32; ++k) acc = fmaf(edge_emb[r * 32 + k], fc_e_W[k * 128 + t], acc);
      sef[r][t] = acc;
    }
  }
  __syncthreads();
  if (t == 0) { int r = 0; for (int k = 0; k < 4; ++k) { wbs[k] = r; r += wsm[k]; } }
  __syncthreads();
  int ex = wbs[wv] + inc - s;
#pragma unroll
  for (int j = 0; j < 4; ++j) {
    int b = 4 * t + j;
    if (b < nb) { bbase[b] = ex; bnext[b] = ex; }
    ex += c[j];
  }
  if (t == 0) bbase[nb] = ne;
  if (t < 32) {
    int r = t >> 2, h = t & 3;
    float acc = 0.f;
#pragma unroll
    for (int e2 = 0; e2 < 32; ++e2) acc += sef[r][h * 32 + e2] * attn_e[h * 32 + e2];
    ee[r * NH + h] = acc;
  }
}

// ---- P2: multisplit edges into nb contiguous buckets; rec = src|et<<17|dlocal<<20 ----
__global__ __launch_bounds__(256) void k_msplit(
    const int* __restrict__ src, const int* __restrict__ dst, const int* __restrict__ et,
    int* __restrict__ bnext, unsigned* __restrict__ ebuf, int ne, int nb)
{
  __shared__ int scnt[NBMAX], sbase[NBMAX], gbase[NBMAX];
  __shared__ unsigned sbuf[CHUNK];     // 32 KB
  __shared__ int wsm[4], wbs[4];
  const int t = threadIdx.x;
  const int base = blockIdx.x * CHUNK;
  for (int i = t; i < nb; i += 256) scnt[i] = 0;
  __syncthreads();
  unsigned pk[CHUNK / 256];
#pragma unroll
  for (int i = 0; i < CHUNK / 256; ++i) {
    int e = base + i * 256 + t;
    pk[i] = 0xFFFFFFFFu;
    if (e < ne) {
      int bin = dst[e] >> 7;
      int slot = atomicAdd(&scnt[bin], 1);
      pk[i] = (unsigned)slot * 1024u + (unsigned)bin;
    }
  }
  __syncthreads();
  // scan scnt -> sbase (thread owns bins 4t..4t+3)
  int c[4], s = 0;
#pragma unroll
  for (int j = 0; j < 4; ++j) { int b = 4 * t + j; c[j] = (b < nb) ? scnt[b] : 0; s += c[j]; }
  const int lane = t & 63, wv = t >> 6;
  int inc = s;
#pragma unroll
  for (int off = 1; off < 64; off <<= 1) {
    int v = __shfl_up(inc, off);
    if (lane >= off) inc += v;
  }
  if (lane == 63) wsm[wv] = inc;
  __syncthreads();
  if (t == 0) { int r = 0; for (int k = 0; k < 4; ++k) { wbs[k] = r; r += wsm[k]; } }
  __syncthreads();
  int ex = wbs[wv] + inc - s;
#pragma unroll
  for (int j = 0; j < 4; ++j) {
    int b = 4 * t + j;
    if (b < nb) {
      sbase[b] = ex;
      if (c[j] > 0) gbase[b] = atomicAdd(&bnext[b], c[j]);
    }
    ex += c[j];
  }
  __syncthreads();
#pragma unroll
  for (int i = 0; i < CHUNK / 256; ++i) {
    int e = base + i * 256 + t;
    if (e < ne) {
      unsigned p = pk[i];
      int bin = (int)(p & 1023u);
      int slot = (int)(p >> 10);
      int d = dst[e];
      unsigned rec = (unsigned)src[e] | ((unsigned)et[e] << 17) | ((unsigned)(d & 127) << 20);
      sbuf[sbase[bin] + slot] = rec;
    }
  }
  __syncthreads();
  // copy-out: wave wv handles bins wv, wv+4, ...
  for (int b = wv; b < nb; b += 4) {
    int cnt = scnt[b];
    int sb = sbase[b], gb = gbase[b];
    for (int i2 = lane; i2 < cnt; i2 += 64)
      ebuf[gb + i2] = sbuf[sb + i2];
  }
}

// ---- P3: per-bucket softmax + aggregate, all accumulation in LDS ----
__global__ __launch_bounds__(256) void k_baggr(
    const unsigned* __restrict__ ebuf, const int* __restrict__ bbase,
    const float* __restrict__ el, const float4* __restrict__ er4,
    const float* __restrict__ eeg, const uint4* __restrict__ featq,
    float4* __restrict__ out4, int n)
{
  __shared__ float acc[BN][HD];     // 32 KB
  __shared__ float den[BN][NH];     // 2 KB
  __shared__ float s_er[BN][NH];    // 2 KB
  __shared__ float s_ee[32];
  const int t = threadIdx.x;
  const int node0 = blockIdx.x * BN;
  for (int i = t; i < BN * HD / 4; i += 256)
    ((float4*)acc)[i] = make_float4(0.f, 0.f, 0.f, 0.f);
  for (int i = t; i < BN; i += 256) {
    int node = node0 + i;
    float4 v = (node < n) ? er4[node] : make_float4(0.f, 0.f, 0.f, 0.f);
    s_er[i][0] = v.x; s_er[i][1] = v.y; s_er[i][2] = v.z; s_er[i][3] = v.w;
    den[i][0] = 0.f; den[i][1] = 0.f; den[i][2] = 0.f; den[i][3] = 0.f;
  }
  if (t < 32) s_ee[t] = eeg[t];
  __syncthreads();
  const int beg = bbase[blockIdx.x], end = bbase[blockIdx.x + 1];
  const int lane = t & 63, wv = t >> 6;
  const int l = lane & 7;       // dim octet: dims 8l..8l+7
  const int q = lane >> 3;      // 8 records in flight per wave
  const int h = l >> 1;         // head for this lane's dims
  for (int i = beg + wv * 8 + q; i < end; i += 32) {
    unsigned r = ebuf[i];
    int s  = (int)(r & 0x1FFFFu);
    int tt = (int)((r >> 17) & 7u);
    int ld = (int)(r >> 20);
    float sv = el[s * NH + h] + s_er[ld][h] + s_ee[tt * NH + h];
    sv = sv > 0.f ? sv : NEG_SLOPE * sv;
    float p = __expf(sv);
    uint4 u = featq[(size_t)s * 8 + l];           // 8 packed bf16 dims
    atomicAdd(&acc[ld][l * 8 + 0], p * __uint_as_float(u.x << 16));
    atomicAdd(&acc[ld][l * 8 + 1], p * __uint_as_float(u.x & 0xFFFF0000u));
    atomicAdd(&acc[ld][l * 8 + 2], p * __uint_as_float(u.y << 16));
    atomicAdd(&acc[ld][l * 8 + 3], p * __uint_as_float(u.y & 0xFFFF0000u));
    atomicAdd(&acc[ld][l * 8 + 4], p * __uint_as_float(u.z << 16));
    atomicAdd(&acc[ld][l * 8 + 5], p * __uint_as_float(u.z & 0xFFFF0000u));
    atomicAdd(&acc[ld][l * 8 + 6], p * __uint_as_float(u.w << 16));
    atomicAdd(&acc[ld][l * 8 + 7], p * __uint_as_float(u.w & 0xFFFF0000u));
    if ((l & 1) == 0) atomicAdd(&den[ld][h], p);
  }
  __syncthreads();
  for (int i = t; i < BN * 16; i += 256) {
    int ld = i >> 4, d4 = i & 15;
    int node = node0 + ld;
    if (node >= n) continue;
    float dn = den[ld][d4 >> 2];
    float inv = dn > 0.f ? 1.f / dn : 0.f;
    out4[(size_t)node * 16 + d4] = make_float4(
        acc[ld][d4 * 4 + 0] * inv, acc[ld][d4 * 4 + 1] * inv,
        acc[ld][d4 * 4 + 2] * inv, acc[ld][d4 * 4 + 3] * inv);
  }
}

extern "C" void kernel_launch(void* const* d_in, const int* in_sizes, int n_in,
                              void* d_out, int out_size, void* d_ws, size_t ws_size,
                              hipStream_t stream)
{
  const float* x        = (const float*)d_in[0];
  const int*   src      = (const int*)d_in[1];
  const int*   dst      = (const int*)d_in[2];
  const int*   etype    = (const int*)d_in[3];
  const float* fcW      = (const float*)d_in[4];
  const float* fceW     = (const float*)d_in[5];
  const float* edge_emb = (const float*)d_in[6];
  const float* attn_l   = (const float*)d_in[7];
  const float* attn_r   = (const float*)d_in[8];
  const float* attn_e   = (const float*)d_in[9];
  float* out = (float*)d_out;

  const int n  = in_sizes[0] / IN_DIM;      // 100000
  const int ne = in_sizes[1];               // 1600000
  const int nb = (n + BN - 1) / BN;         // 782 buckets

  char* ws = (char*)d_ws;
  size_t off = 0;
  unsigned short* featb = (unsigned short*)(ws + off); off += (size_t)n * HD * sizeof(unsigned short);
  float* el    = (float*)(ws + off); off += (size_t)n * NH * sizeof(float);
  float* er    = (float*)(ws + off); off += (size_t)n * NH * sizeof(float);
  float* ee    = (float*)(ws + off); off += 256;
  int* bincnt  = (int*)(ws + off);   off += NBMAX * sizeof(int);
  int* bbase   = (int*)(ws + off);   off += (NBMAX + 1) * sizeof(int);
  int* bnext   = (int*)(ws + off);   off += NBMAX * sizeof(int);
  unsigned* ebuf = (unsigned*)(ws + off); off += (size_t)ne * sizeof(unsigned);

  hipMemsetAsync(bincnt, 0, NBMAX * sizeof(int), stream);

  k_bincnt<<<512, 256, 0, stream>>>(dst, bincnt, ne, nb);
  k_scan_ee<<<1, 256, 0, stream>>>(bincnt, bbase, bnext, nb, ne,
                                   edge_emb, fceW, attn_e, ee);
  k_msplit<<<(ne + CHUNK - 1) / CHUNK, 256, 0, stream>>>(src, dst, etype, bnext, ebuf, ne, nb);
  k1_mfma<<<(n + 63) / 64, 256, 0, stream>>>(x, fcW, attn_l, attn_r, featb,
                                             (float4*)el, (float4*)er, n);
  k_baggr<<<nb, 256, 0, stream>>>(ebuf, bbase, el, (const float4*)er, ee,
                                  (const uint4*)featb, (float4*)out, n);
}

// Round 9
// 197.960 us; speedup vs baseline: 4.3029x; 4.3029x over previous
//
#include <hip/hip_runtime.h>

#define NH 4
#define HD 64
#define IN_DIM 128
#define NEG_SLOPE 0.2f
#define BN 128          // dst nodes per bucket
#define NBMAX 1024      // max buckets (n <= 131072)
#define CHUNK 8192      // edges per multisplit block
#define SBUFSZ 4096     // per-bucket record capacity (mean 2048, sigma ~45)

typedef short bf8 __attribute__((ext_vector_type(8)));   // 8 bf16 in 4 VGPRs
typedef float f4  __attribute__((ext_vector_type(4)));

__device__ inline unsigned short f2bf(float f) {   // RNE fp32 -> bf16
  unsigned u = __float_as_uint(f);
  u += 0x7FFFu + ((u >> 16) & 1u);
  return (unsigned short)(u >> 16);
}

// ---- K1: feat(bf16) = x @ fc_W via MFMA, + el/er per node ----
__global__ __launch_bounds__(256) void k1_mfma(
    const float* __restrict__ x, const float* __restrict__ fcW,
    const float* __restrict__ attn_l, const float* __restrict__ attn_r,
    unsigned short* __restrict__ featb, float4* __restrict__ el4, float4* __restrict__ er4,
    int n)
{
  __shared__ unsigned short wt[HD][IN_DIM + 8];   // W^T bf16, padded
  for (int idx = threadIdx.x; idx < IN_DIM * HD; idx += 256) {
    int k = idx >> 6, j = idx & 63;
    wt[j][k] = f2bf(fcW[idx]);
  }
  __syncthreads();

  const int w  = threadIdx.x >> 6;    // wave 0..3
  const int l  = threadIdx.x & 63;
  const int lr = l & 15;
  const int lg = l >> 4;
  const int rowbase = blockIdx.x * 64 + w * 16;

  int arow = rowbase + lr;
  if (arow >= n) arow = n - 1;                     // clamp; stores predicated
  const float* xp = x + (size_t)arow * IN_DIM + lg * 8;

  f4 acc[4] = {};                                  // one per n-tile (= head)
#pragma unroll
  for (int kc = 0; kc < 4; ++kc) {
    float4 a0 = *(const float4*)(xp + kc * 32);
    float4 a1 = *(const float4*)(xp + kc * 32 + 4);
    bf8 af;
    af[0] = (short)f2bf(a0.x); af[1] = (short)f2bf(a0.y);
    af[2] = (short)f2bf(a0.z); af[3] = (short)f2bf(a0.w);
    af[4] = (short)f2bf(a1.x); af[5] = (short)f2bf(a1.y);
    af[6] = (short)f2bf(a1.z); af[7] = (short)f2bf(a1.w);
#pragma unroll
    for (int nt = 0; nt < 4; ++nt) {
      bf8 bfr = *(const bf8*)&wt[nt * 16 + lr][kc * 32 + lg * 8];
      acc[nt] = __builtin_amdgcn_mfma_f32_16x16x32_bf16(af, bfr, acc[nt], 0, 0, 0);
    }
  }

  float al[NH], ar[NH];
#pragma unroll
  for (int h = 0; h < NH; ++h) { al[h] = attn_l[h * 16 + lr]; ar[h] = attn_r[h * 16 + lr]; }

#pragma unroll
  for (int r = 0; r < 4; ++r) {
    int grow = rowbase + lg * 4 + r;
    bool ok = grow < n;
    if (ok) {
#pragma unroll
      for (int nt = 0; nt < 4; ++nt)
        featb[(size_t)grow * HD + nt * 16 + lr] = f2bf(acc[nt][r]);
    }
    float pl[NH], pr[NH];
#pragma unroll
    for (int h = 0; h < NH; ++h) { pl[h] = acc[h][r] * al[h]; pr[h] = acc[h][r] * ar[h]; }
#pragma unroll
    for (int off = 1; off < 16; off <<= 1) {
#pragma unroll
      for (int h = 0; h < NH; ++h) {
        pl[h] += __shfl_xor(pl[h], off);
        pr[h] += __shfl_xor(pr[h], off);
      }
    }
    if (ok && lr == 0) {
      el4[grow] = make_float4(pl[0], pl[1], pl[2], pl[3]);
      er4[grow] = make_float4(pr[0], pr[1], pr[2], pr[3]);
    }
  }
}

// ---- P0: bucket counts (bin = dst>>7), LDS histogram ----
__global__ __launch_bounds__(256) void k_bincnt(
    const int* __restrict__ dst, int* __restrict__ bincnt, int ne, int nb)
{
  __shared__ int lc[NBMAX];
  for (int i = threadIdx.x; i < nb; i += 256) lc[i] = 0;
  __syncthreads();
  for (int e = blockIdx.x * 256 + threadIdx.x; e < ne; e += gridDim.x * 256)
    atomicAdd(&lc[dst[e] >> 7], 1);
  __syncthreads();
  for (int i = threadIdx.x; i < nb; i += 256)
    if (lc[i]) atomicAdd(&bincnt[i], lc[i]);
}

// ---- P1: scan bucket counts -> bbase/bnext (single block) + tiny ee fused ----
__global__ __launch_bounds__(256) void k_scan_ee(
    const int* __restrict__ bincnt, int* __restrict__ bbase, int* __restrict__ bnext,
    int nb, int ne,
    const float* __restrict__ edge_emb, const float* __restrict__ fc_e_W,
    const float* __restrict__ attn_e, float* __restrict__ ee)
{
  __shared__ int wsm[4], wbs[4];
  __shared__ float sef[8][128];
  const int t = threadIdx.x;
  int c[4], s = 0;
#pragma unroll
  for (int j = 0; j < 4; ++j) { int b = 4 * t + j; c[j] = (b < nb) ? bincnt[b] : 0; s += c[j]; }
  const int lane = t & 63, wv = t >> 6;
  int inc = s;
#pragma unroll
  for (int off = 1; off < 64; off <<= 1) {
    int v = __shfl_up(inc, off);
    if (lane >= off) inc += v;
  }
  if (lane == 63) wsm[wv] = inc;
  if (t < 128) {
    for (int r = 0; r < 8; ++r) {
      float acc = 0.f;
#pragma unroll
      for (int k = 0; k < 32; ++k) acc = fmaf(edge_emb[r * 32 + k], fc_e_W[k * 128 + t], acc);
      sef[r][t] = acc;
    }
  }
  __syncthreads();
  if (t == 0) { int r = 0; for (int k = 0; k < 4; ++k) { wbs[k] = r; r += wsm[k]; } }
  __syncthreads();
  int ex = wbs[wv] + inc - s;
#pragma unroll
  for (int j = 0; j < 4; ++j) {
    int b = 4 * t + j;
    if (b < nb) { bbase[b] = ex; bnext[b] = ex; }
    ex += c[j];
  }
  if (t == 0) bbase[nb] = ne;
  if (t < 32) {
    int r = t >> 2, h = t & 3;
    float acc = 0.f;
#pragma unroll
    for (int e2 = 0; e2 < 32; ++e2) acc += sef[r][h * 32 + e2] * attn_e[h * 32 + e2];
    ee[r * NH + h] = acc;
  }
}

// ---- P2: multisplit edges into nb contiguous buckets; rec = src|et<<17|dlocal<<20 ----
__global__ __launch_bounds__(256) void k_msplit(
    const int* __restrict__ src, const int* __restrict__ dst, const int* __restrict__ et,
    int* __restrict__ bnext, unsigned* __restrict__ ebuf, int ne, int nb)
{
  __shared__ int scnt[NBMAX], sbase[NBMAX], gbase[NBMAX];
  __shared__ unsigned sbuf[CHUNK];     // 32 KB
  __shared__ int wsm[4], wbs[4];
  const int t = threadIdx.x;
  const int base = blockIdx.x * CHUNK;
  for (int i = t; i < nb; i += 256) scnt[i] = 0;
  __syncthreads();
  unsigned pk[CHUNK / 256];
#pragma unroll
  for (int i = 0; i < CHUNK / 256; ++i) {
    int e = base + i * 256 + t;
    pk[i] = 0xFFFFFFFFu;
    if (e < ne) {
      int bin = dst[e] >> 7;
      int slot = atomicAdd(&scnt[bin], 1);
      pk[i] = (unsigned)slot * 1024u + (unsigned)bin;
    }
  }
  __syncthreads();
  int c[4], s = 0;
#pragma unroll
  for (int j = 0; j < 4; ++j) { int b = 4 * t + j; c[j] = (b < nb) ? scnt[b] : 0; s += c[j]; }
  const int lane = t & 63, wv = t >> 6;
  int inc = s;
#pragma unroll
  for (int off = 1; off < 64; off <<= 1) {
    int v = __shfl_up(inc, off);
    if (lane >= off) inc += v;
  }
  if (lane == 63) wsm[wv] = inc;
  __syncthreads();
  if (t == 0) { int r = 0; for (int k = 0; k < 4; ++k) { wbs[k] = r; r += wsm[k]; } }
  __syncthreads();
  int ex = wbs[wv] + inc - s;
#pragma unroll
  for (int j = 0; j < 4; ++j) {
    int b = 4 * t + j;
    if (b < nb) {
      sbase[b] = ex;
      if (c[j] > 0) gbase[b] = atomicAdd(&bnext[b], c[j]);
    }
    ex += c[j];
  }
  __syncthreads();
#pragma unroll
  for (int i = 0; i < CHUNK / 256; ++i) {
    int e = base + i * 256 + t;
    if (e < ne) {
      unsigned p = pk[i];
      int bin = (int)(p & 1023u);
      int slot = (int)(p >> 10);
      int d = dst[e];
      unsigned rec = (unsigned)src[e] | ((unsigned)et[e] << 17) | ((unsigned)(d & 127) << 20);
      sbuf[sbase[bin] + slot] = rec;
    }
  }
  __syncthreads();
  for (int b = wv; b < nb; b += 4) {
    int cnt = scnt[b];
    int sb = sbase[b], gb = gbase[b];
    for (int i2 = lane; i2 < cnt; i2 += 64)
      ebuf[gb + i2] = sbuf[sb + i2];
  }
}

// ---- P3: per-bucket LDS counting sort by dlocal + register-accum aggregation ----
__global__ __launch_bounds__(256) void k_sortagg(
    const unsigned* __restrict__ ebuf, const int* __restrict__ bbase,
    const float* __restrict__ el, const float4* __restrict__ er4,
    const float* __restrict__ eeg, const uint4* __restrict__ featq,
    float4* __restrict__ out4, int n)
{
  __shared__ unsigned sbuf[SBUFSZ];    // 16 KB
  __shared__ int cnt[BN];              // histogram, then scatter cursor
  __shared__ int sb[BN + 1];           // segment bases (bucket-local)
  __shared__ float s_er[BN][NH];       // 2 KB
  __shared__ float s_ee[32];
  __shared__ int wsum[2];
  const int t = threadIdx.x;
  const int node0 = blockIdx.x * BN;
  const int beg = bbase[blockIdx.x], end = bbase[blockIdx.x + 1];
  const int count = end - beg;
  for (int i = t; i < BN; i += 256) {
    cnt[i] = 0;
    int node = node0 + i;
    float4 v = (node < n) ? er4[node] : make_float4(0.f, 0.f, 0.f, 0.f);
    s_er[i][0] = v.x; s_er[i][1] = v.y; s_er[i][2] = v.z; s_er[i][3] = v.w;
  }
  if (t < 32) s_ee[t] = eeg[t];
  __syncthreads();

  const int lane = t & 63, wv = t >> 6;
  const int q = lane >> 3;      // 8 records in flight per wave
  const int l = lane & 7;       // dim octet: dims 8l..8l+7
  const int h = l >> 1;         // head for this lane's dims
  const bool sorted = (count <= SBUFSZ);

  if (sorted) {
    // pass 1: histogram of dlocal
    for (int i = beg + t; i < end; i += 256)
      atomicAdd(&cnt[ebuf[i] >> 20], 1);
    __syncthreads();
    // scan 128 bins with waves 0-1
    int cc = 0, inc = 0;
    if (t < 128) {
      cc = cnt[t];
      inc = cc;
#pragma unroll
      for (int off = 1; off < 64; off <<= 1) {
        int v = __shfl_up(inc, off);
        if (lane >= off) inc += v;
      }
      if (lane == 63) wsum[wv] = inc;
    }
    __syncthreads();
    if (t < 128) {
      int ex = (wv ? wsum[0] : 0) + inc - cc;
      sb[t] = ex;
      cnt[t] = ex;              // scatter cursor
      if (t == 127) sb[128] = ex + cc;
    }
    __syncthreads();
    // pass 2: place records
    for (int i = beg + t; i < end; i += 256) {
      unsigned r = ebuf[i];
      int pos = atomicAdd(&cnt[r >> 20], 1);
      sbuf[pos] = r;
    }
    __syncthreads();
  }

  // aggregation: wave wv owns dsts [wv*32, wv*32+32)
  for (int ld = wv * 32; ld < wv * 32 + 32; ++ld) {
    float erh = s_er[ld][h];
    float a0 = 0.f, a1 = 0.f, a2 = 0.f, a3 = 0.f;
    float a4 = 0.f, a5 = 0.f, a6 = 0.f, a7 = 0.f, den = 0.f;
    if (sorted) {
      const int s0 = sb[ld], s1 = sb[ld + 1];
      for (int i = s0 + q; i < s1; i += 8) {
        unsigned r = sbuf[i];
        int s  = (int)(r & 0x1FFFFu);
        int tt = (int)((r >> 17) & 7u);
        float sv = el[s * NH + h] + erh + s_ee[tt * NH + h];
        sv = sv > 0.f ? sv : NEG_SLOPE * sv;
        float p = __expf(sv);
        den += p;
        uint4 u = featq[(size_t)s * 8 + l];
        a0 = fmaf(p, __uint_as_float(u.x << 16), a0);
        a1 = fmaf(p, __uint_as_float(u.x & 0xFFFF0000u), a1);
        a2 = fmaf(p, __uint_as_float(u.y << 16), a2);
        a3 = fmaf(p, __uint_as_float(u.y & 0xFFFF0000u), a3);
        a4 = fmaf(p, __uint_as_float(u.z << 16), a4);
        a5 = fmaf(p, __uint_as_float(u.z & 0xFFFF0000u), a5);
        a6 = fmaf(p, __uint_as_float(u.w << 16), a6);
        a7 = fmaf(p, __uint_as_float(u.w & 0xFFFF0000u), a7);
      }
    } else {
      // fallback (statistically never): filtered direct scan of the bucket
      for (int i = beg + q; i < end; i += 8) {
        unsigned r = ebuf[i];
        if ((int)(r >> 20) != ld) continue;
        int s  = (int)(r & 0x1FFFFu);
        int tt = (int)((r >> 17) & 7u);
        float sv = el[s * NH + h] + erh + s_ee[tt * NH + h];
        sv = sv > 0.f ? sv : NEG_SLOPE * sv;
        float p = __expf(sv);
        den += p;
        uint4 u = featq[(size_t)s * 8 + l];
        a0 = fmaf(p, __uint_as_float(u.x << 16), a0);
        a1 = fmaf(p, __uint_as_float(u.x & 0xFFFF0000u), a1);
        a2 = fmaf(p, __uint_as_float(u.y << 16), a2);
        a3 = fmaf(p, __uint_as_float(u.y & 0xFFFF0000u), a3);
        a4 = fmaf(p, __uint_as_float(u.z << 16), a4);
        a5 = fmaf(p, __uint_as_float(u.z & 0xFFFF0000u), a5);
        a6 = fmaf(p, __uint_as_float(u.w << 16), a6);
        a7 = fmaf(p, __uint_as_float(u.w & 0xFFFF0000u), a7);
      }
    }
#pragma unroll
    for (int off = 8; off <= 32; off <<= 1) {
      den += __shfl_xor(den, off);
      a0 += __shfl_xor(a0, off); a1 += __shfl_xor(a1, off);
      a2 += __shfl_xor(a2, off); a3 += __shfl_xor(a3, off);
      a4 += __shfl_xor(a4, off); a5 += __shfl_xor(a5, off);
      a6 += __shfl_xor(a6, off); a7 += __shfl_xor(a7, off);
    }
    if (q == 0) {
      int node = node0 + ld;
      if (node < n) {
        float inv = den > 0.f ? 1.f / den : 0.f;
        float4* op = out4 + (size_t)node * 16 + l * 2;
        op[0] = make_float4(a0 * inv, a1 * inv, a2 * inv, a3 * inv);
        op[1] = make_float4(a4 * inv, a5 * inv, a6 * inv, a7 * inv);
      }
    }
  }
}

extern "C" void kernel_launch(void* const* d_in, const int* in_sizes, int n_in,
                              void* d_out, int out_size, void* d_ws, size_t ws_size,
                              hipStream_t stream)
{
  const float* x        = (const float*)d_in[0];
  const int*   src      = (const int*)d_in[1];
  const int*   dst      = (const int*)d_in[2];
  const int*   etype    = (const int*)d_in[3];
  const float* fcW      = (const float*)d_in[4];
  const float* fceW     = (const float*)d_in[5];
  const float* edge_emb = (const float*)d_in[6];
  const float* attn_l   = (const float*)d_in[7];
  const float* attn_r   = (const float*)d_in[8];
  const float* attn_e   = (const float*)d_in[9];
  float* out = (float*)d_out;

  const int n  = in_sizes[0] / IN_DIM;      // 100000
  const int ne = in_sizes[1];               // 1600000
  const int nb = (n + BN - 1) / BN;         // 782 buckets

  char* ws = (char*)d_ws;
  size_t off = 0;
  unsigned short* featb = (unsigned short*)(ws + off); off += (size_t)n * HD * sizeof(unsigned short);
  float* el    = (float*)(ws + off); off += (size_t)n * NH * sizeof(float);
  float* er    = (float*)(ws + off); off += (size_t)n * NH * sizeof(float);
  float* ee    = (float*)(ws + off); off += 256;
  int* bincnt  = (int*)(ws + off);   off += NBMAX * sizeof(int);
  int* bbase   = (int*)(ws + off);   off += (NBMAX + 1) * sizeof(int);
  int* bnext   = (int*)(ws + off);   off += NBMAX * sizeof(int);
  unsigned* ebuf = (unsigned*)(ws + off); off += (size_t)ne * sizeof(unsigned);

  hipMemsetAsync(bincnt, 0, NBMAX * sizeof(int), stream);

  k_bincnt<<<512, 256, 0, stream>>>(dst, bincnt, ne, nb);
  k_scan_ee<<<1, 256, 0, stream>>>(bincnt, bbase, bnext, nb, ne,
                                   edge_emb, fceW, attn_e, ee);
  k_msplit<<<(ne + CHUNK - 1) / CHUNK, 256, 0, stream>>>(src, dst, etype, bnext, ebuf, ne, nb);
  k1_mfma<<<(n + 63) / 64, 256, 0, stream>>>(x, fcW, attn_l, attn_r, featb,
                                             (float4*)el, (float4*)er, n);
  k_sortagg<<<nb, 256, 0, stream>>>(ebuf, bbase, el, (const float4*)er, ee,
                                    (const uint4*)featb, (float4*)out, n);
}

// Round 10
// 178.720 us; speedup vs baseline: 4.7661x; 1.1077x over previous
//
#include <hip/hip_runtime.h>

#define NH 4
#define HD 64
#define IN_DIM 128
#define NEG_SLOPE 0.2f
#define BN 128          // dst nodes per bucket
#define NBMAX 1024      // max buckets (n <= 131072)
#define CHUNK 4096      // edges per multisplit block
#define EPT (CHUNK/256) // edges per thread in multisplit
#define SBUFSZ 4096     // per-bucket record capacity (mean 2048, sigma ~45)

typedef short bf8 __attribute__((ext_vector_type(8)));   // 8 bf16 in 4 VGPRs
typedef float f4  __attribute__((ext_vector_type(4)));

__device__ inline unsigned short f2bf(float f) {   // RNE fp32 -> bf16
  unsigned u = __float_as_uint(f);
  u += 0x7FFFu + ((u >> 16) & 1u);
  return (unsigned short)(u >> 16);
}

// ---- K1: feat(bf16) = x @ fc_W via MFMA, + el/er per node ----
__global__ __launch_bounds__(256) void k1_mfma(
    const float* __restrict__ x, const float* __restrict__ fcW,
    const float* __restrict__ attn_l, const float* __restrict__ attn_r,
    unsigned short* __restrict__ featb, float4* __restrict__ el4, float4* __restrict__ er4,
    int n)
{
  __shared__ unsigned short wt[HD][IN_DIM + 8];   // W^T bf16, padded
  for (int idx = threadIdx.x; idx < IN_DIM * HD; idx += 256) {
    int k = idx >> 6, j = idx & 63;
    wt[j][k] = f2bf(fcW[idx]);
  }
  __syncthreads();

  const int w  = threadIdx.x >> 6;    // wave 0..3
  const int l  = threadIdx.x & 63;
  const int lr = l & 15;
  const int lg = l >> 4;
  const int rowbase = blockIdx.x * 64 + w * 16;

  int arow = rowbase + lr;
  if (arow >= n) arow = n - 1;                     // clamp; stores predicated
  const float* xp = x + (size_t)arow * IN_DIM + lg * 8;

  f4 acc[4] = {};                                  // one per n-tile (= head)
#pragma unroll
  for (int kc = 0; kc < 4; ++kc) {
    float4 a0 = *(const float4*)(xp + kc * 32);
    float4 a1 = *(const float4*)(xp + kc * 32 + 4);
    bf8 af;
    af[0] = (short)f2bf(a0.x); af[1] = (short)f2bf(a0.y);
    af[2] = (short)f2bf(a0.z); af[3] = (short)f2bf(a0.w);
    af[4] = (short)f2bf(a1.x); af[5] = (short)f2bf(a1.y);
    af[6] = (short)f2bf(a1.z); af[7] = (short)f2bf(a1.w);
#pragma unroll
    for (int nt = 0; nt < 4; ++nt) {
      bf8 bfr = *(const bf8*)&wt[nt * 16 + lr][kc * 32 + lg * 8];
      acc[nt] = __builtin_amdgcn_mfma_f32_16x16x32_bf16(af, bfr, acc[nt], 0, 0, 0);
    }
  }

  float al[NH], ar[NH];
#pragma unroll
  for (int h = 0; h < NH; ++h) { al[h] = attn_l[h * 16 + lr]; ar[h] = attn_r[h * 16 + lr]; }

#pragma unroll
  for (int r = 0; r < 4; ++r) {
    int grow = rowbase + lg * 4 + r;
    bool ok = grow < n;
    if (ok) {
#pragma unroll
      for (int nt = 0; nt < 4; ++nt)
        featb[(size_t)grow * HD + nt * 16 + lr] = f2bf(acc[nt][r]);
    }
    float pl[NH], pr[NH];
#pragma unroll
    for (int h = 0; h < NH; ++h) { pl[h] = acc[h][r] * al[h]; pr[h] = acc[h][r] * ar[h]; }
#pragma unroll
    for (int off = 1; off < 16; off <<= 1) {
#pragma unroll
      for (int h = 0; h < NH; ++h) {
        pl[h] += __shfl_xor(pl[h], off);
        pr[h] += __shfl_xor(pr[h], off);
      }
    }
    if (ok && lr == 0) {
      el4[grow] = make_float4(pl[0], pl[1], pl[2], pl[3]);
      er4[grow] = make_float4(pr[0], pr[1], pr[2], pr[3]);
    }
  }
}

// ---- P0: bucket counts (bin = dst>>7), LDS histogram ----
__global__ __launch_bounds__(256) void k_bincnt(
    const int* __restrict__ dst, int* __restrict__ bincnt, int ne, int nb)
{
  __shared__ int lc[NBMAX];
  for (int i = threadIdx.x; i < nb; i += 256) lc[i] = 0;
  __syncthreads();
  for (int e = blockIdx.x * 256 + threadIdx.x; e < ne; e += gridDim.x * 256)
    atomicAdd(&lc[dst[e] >> 7], 1);
  __syncthreads();
  for (int i = threadIdx.x; i < nb; i += 256)
    if (lc[i]) atomicAdd(&bincnt[i], lc[i]);
}

// ---- P1: scan bucket counts -> bbase/bnext (single block) + tiny ee fused ----
__global__ __launch_bounds__(256) void k_scan_ee(
    const int* __restrict__ bincnt, int* __restrict__ bbase, int* __restrict__ bnext,
    int nb, int ne,
    const float* __restrict__ edge_emb, const float* __restrict__ fc_e_W,
    const float* __restrict__ attn_e, float* __restrict__ ee)
{
  __shared__ int wsm[4], wbs[4];
  __shared__ float sef[8][128];
  const int t = threadIdx.x;
  int c[4], s = 0;
#pragma unroll
  for (int j = 0; j < 4; ++j) { int b = 4 * t + j; c[j] = (b < nb) ? bincnt[b] : 0; s += c[j]; }
  const int lane = t & 63, wv = t >> 6;
  int inc = s;
#pragma unroll
  for (int off = 1; off < 64; off <<= 1) {
    int v = __shfl_up(inc, off);
    if (lane >= off) inc += v;
  }
  if (lane == 63) wsm[wv] = inc;
  if (t < 128) {
    for (int r = 0; r < 8; ++r) {
      float acc = 0.f;
#pragma unroll
      for (int k = 0; k < 32; ++k) acc = fmaf(edge_emb[r * 32 + k], fc_e_W[k * 128 + t], acc);
      sef[r][t] = acc;
    }
  }
  __syncthreads();
  if (t == 0) { int r = 0; for (int k = 0; k < 4; ++k) { wbs[k] = r; r += wsm[k]; } }
  __syncthreads();
  int ex = wbs[wv] + inc - s;
#pragma unroll
  for (int j = 0; j < 4; ++j) {
    int b = 4 * t + j;
    if (b < nb) { bbase[b] = ex; bnext[b] = ex; }
    ex += c[j];
  }
  if (t == 0) bbase[nb] = ne;
  if (t < 32) {
    int r = t >> 2, h = t & 3;
    float acc = 0.f;
#pragma unroll
    for (int e2 = 0; e2 < 32; ++e2) acc += sef[r][h * 32 + e2] * attn_e[h * 32 + e2];
    ee[r * NH + h] = acc;
  }
}

// ---- P2: multisplit edges into nb contiguous buckets; rec = src|et<<17|dlocal<<20 ----
__global__ __launch_bounds__(256) void k_msplit(
    const int* __restrict__ src, const int* __restrict__ dst, const int* __restrict__ et,
    int* __restrict__ bnext, unsigned* __restrict__ ebuf, int ne, int nb)
{
  __shared__ int scnt[NBMAX], sbase[NBMAX], gbase[NBMAX];   // 12 KB
  __shared__ unsigned sbuf[CHUNK];                           // 16 KB
  __shared__ int wsm[4], wbs[4];
  const int t = threadIdx.x;
  const int base = blockIdx.x * CHUNK;
  for (int i = t; i < nb; i += 256) scnt[i] = 0;
  __syncthreads();
  unsigned pk[EPT], rc[EPT];
#pragma unroll
  for (int i = 0; i < EPT; ++i) {
    int e = base + i * 256 + t;
    pk[i] = 0xFFFFFFFFu;
    if (e < ne) {
      int d = dst[e];
      int bin = d >> 7;
      rc[i] = (unsigned)src[e] | ((unsigned)et[e] << 17) | ((unsigned)(d & 127) << 20);
      int slot = atomicAdd(&scnt[bin], 1);
      pk[i] = (unsigned)slot * 1024u + (unsigned)bin;
    }
  }
  __syncthreads();
  int c[4], s = 0;
#pragma unroll
  for (int j = 0; j < 4; ++j) { int b = 4 * t + j; c[j] = (b < nb) ? scnt[b] : 0; s += c[j]; }
  const int lane = t & 63, wv = t >> 6;
  int inc = s;
#pragma unroll
  for (int off = 1; off < 64; off <<= 1) {
    int v = __shfl_up(inc, off);
    if (lane >= off) inc += v;
  }
  if (lane == 63) wsm[wv] = inc;
  __syncthreads();
  if (t == 0) { int r = 0; for (int k = 0; k < 4; ++k) { wbs[k] = r; r += wsm[k]; } }
  __syncthreads();
  int ex = wbs[wv] + inc - s;
#pragma unroll
  for (int j = 0; j < 4; ++j) {
    int b = 4 * t + j;
    if (b < nb) {
      sbase[b] = ex;
      if (c[j] > 0) gbase[b] = atomicAdd(&bnext[b], c[j]);
    }
    ex += c[j];
  }
  __syncthreads();
#pragma unroll
  for (int i = 0; i < EPT; ++i) {
    if (pk[i] != 0xFFFFFFFFu) {
      int bin = (int)(pk[i] & 1023u);
      int slot = (int)(pk[i] >> 10);
      sbuf[sbase[bin] + slot] = rc[i];
    }
  }
  __syncthreads();
  // copy-out: 8 record-lanes per bin, 8 bins per wave-iteration (all lanes active)
  const int sub = lane >> 3, rl = lane & 7;
  for (int b0 = wv * 8 + sub; b0 < nb; b0 += 32) {
    int cnt = scnt[b0];
    if (cnt > 0) {
      int sb = sbase[b0], gb = gbase[b0];
      for (int i2 = rl; i2 < cnt; i2 += 8)
        ebuf[gb + i2] = sbuf[sb + i2];
    }
  }
}

// ---- P3: per-bucket LDS counting sort by dlocal + register-accum aggregation ----
__global__ __launch_bounds__(256) void k_sortagg(
    const unsigned* __restrict__ ebuf, const int* __restrict__ bbase,
    const float* __restrict__ el, const float4* __restrict__ er4,
    const float* __restrict__ eeg, const uint4* __restrict__ featq,
    float4* __restrict__ out4, int n)
{
  __shared__ unsigned sbuf[SBUFSZ];    // 16 KB
  __shared__ int cnt[BN];              // histogram, then scatter cursor
  __shared__ int sb[BN + 1];           // segment bases (bucket-local)
  __shared__ float s_er[BN][NH];       // 2 KB
  __shared__ float s_ee[32];
  __shared__ int wsum[2];
  const int t = threadIdx.x;
  const int node0 = blockIdx.x * BN;
  const int beg = bbase[blockIdx.x], end = bbase[blockIdx.x + 1];
  const int count = end - beg;
  for (int i = t; i < BN; i += 256) {
    cnt[i] = 0;
    int node = node0 + i;
    float4 v = (node < n) ? er4[node] : make_float4(0.f, 0.f, 0.f, 0.f);
    s_er[i][0] = v.x; s_er[i][1] = v.y; s_er[i][2] = v.z; s_er[i][3] = v.w;
  }
  if (t < 32) s_ee[t] = eeg[t];
  __syncthreads();

  const int lane = t & 63, wv = t >> 6;
  const int q = lane >> 3;      // 8 records in flight per wave
  const int l = lane & 7;       // dim octet: dims 8l..8l+7
  const int h = l >> 1;         // head for this lane's dims
  const bool sorted = (count <= SBUFSZ);

  if (sorted) {
    for (int i = beg + t; i < end; i += 256)
      atomicAdd(&cnt[ebuf[i] >> 20], 1);
    __syncthreads();
    int cc = 0, inc = 0;
    if (t < 128) {
      cc = cnt[t];
      inc = cc;
#pragma unroll
      for (int off = 1; off < 64; off <<= 1) {
        int v = __shfl_up(inc, off);
        if (lane >= off) inc += v;
      }
      if (lane == 63) wsum[wv] = inc;
    }
    __syncthreads();
    if (t < 128) {
      int ex = (wv ? wsum[0] : 0) + inc - cc;
      sb[t] = ex;
      cnt[t] = ex;              // scatter cursor
      if (t == 127) sb[128] = ex + cc;
    }
    __syncthreads();
    for (int i = beg + t; i < end; i += 256) {
      unsigned r = ebuf[i];
      int pos = atomicAdd(&cnt[r >> 20], 1);
      sbuf[pos] = r;
    }
    __syncthreads();
  }

  for (int ld = wv * 32; ld < wv * 32 + 32; ++ld) {
    float erh = s_er[ld][h];
    float a0 = 0.f, a1 = 0.f, a2 = 0.f, a3 = 0.f;
    float a4 = 0.f, a5 = 0.f, a6 = 0.f, a7 = 0.f, den = 0.f;
    if (sorted) {
      const int s0 = sb[ld], s1 = sb[ld + 1];
      for (int i = s0 + q; i < s1; i += 8) {
        unsigned r = sbuf[i];
        int s  = (int)(r & 0x1FFFFu);
        int tt = (int)((r >> 17) & 7u);
        float sv = el[s * NH + h] + erh + s_ee[tt * NH + h];
        sv = sv > 0.f ? sv : NEG_SLOPE * sv;
        float p = __expf(sv);
        den += p;
        uint4 u = featq[(size_t)s * 8 + l];
        a0 = fmaf(p, __uint_as_float(u.x << 16), a0);
        a1 = fmaf(p, __uint_as_float(u.x & 0xFFFF0000u), a1);
        a2 = fmaf(p, __uint_as_float(u.y << 16), a2);
        a3 = fmaf(p, __uint_as_float(u.y & 0xFFFF0000u), a3);
        a4 = fmaf(p, __uint_as_float(u.z << 16), a4);
        a5 = fmaf(p, __uint_as_float(u.z & 0xFFFF0000u), a5);
        a6 = fmaf(p, __uint_as_float(u.w << 16), a6);
        a7 = fmaf(p, __uint_as_float(u.w & 0xFFFF0000u), a7);
      }
    } else {
      for (int i = beg + q; i < end; i += 8) {
        unsigned r = ebuf[i];
        if ((int)(r >> 20) != ld) continue;
        int s  = (int)(r & 0x1FFFFu);
        int tt = (int)((r >> 17) & 7u);
        float sv = el[s * NH + h] + erh + s_ee[tt * NH + h];
        sv = sv > 0.f ? sv : NEG_SLOPE * sv;
        float p = __expf(sv);
        den += p;
        uint4 u = featq[(size_t)s * 8 + l];
        a0 = fmaf(p, __uint_as_float(u.x << 16), a0);
        a1 = fmaf(p, __uint_as_float(u.x & 0xFFFF0000u), a1);
        a2 = fmaf(p, __uint_as_float(u.y << 16), a2);
        a3 = fmaf(p, __uint_as_float(u.y & 0xFFFF0000u), a3);
        a4 = fmaf(p, __uint_as_float(u.z << 16), a4);
        a5 = fmaf(p, __uint_as_float(u.z & 0xFFFF0000u), a5);
        a6 = fmaf(p, __uint_as_float(u.w << 16), a6);
        a7 = fmaf(p, __uint_as_float(u.w & 0xFFFF0000u), a7);
      }
    }
#pragma unroll
    for (int off = 8; off <= 32; off <<= 1) {
      den += __shfl_xor(den, off);
      a0 += __shfl_xor(a0, off); a1 += __shfl_xor(a1, off);
      a2 += __shfl_xor(a2, off); a3 += __shfl_xor(a3, off);
      a4 += __shfl_xor(a4, off); a5 += __shfl_xor(a5, off);
      a6 += __shfl_xor(a6, off); a7 += __shfl_xor(a7, off);
    }
    if (q == 0) {
      int node = node0 + ld;
      if (node < n) {
        float inv = den > 0.f ? 1.f / den : 0.f;
        float4* op = out4 + (size_t)node * 16 + l * 2;
        op[0] = make_float4(a0 * inv, a1 * inv, a2 * inv, a3 * inv);
        op[1] = make_float4(a4 * inv, a5 * inv, a6 * inv, a7 * inv);
      }
    }
  }
}

extern "C" void kernel_launch(void* const* d_in, const int* in_sizes, int n_in,
                              void* d_out, int out_size, void* d_ws, size_t ws_size,
                              hipStream_t stream)
{
  const float* x        = (const float*)d_in[0];
  const int*   src      = (const int*)d_in[1];
  const int*   dst      = (const int*)d_in[2];
  const int*   etype    = (const int*)d_in[3];
  const float* fcW      = (const float*)d_in[4];
  const float* fceW     = (const float*)d_in[5];
  const float* edge_emb = (const float*)d_in[6];
  const float* attn_l   = (const float*)d_in[7];
  const float* attn_r   = (const float*)d_in[8];
  const float* attn_e   = (const float*)d_in[9];
  float* out = (float*)d_out;

  const int n  = in_sizes[0] / IN_DIM;      // 100000
  const int ne = in_sizes[1];               // 1600000
  const int nb = (n + BN - 1) / BN;         // 782 buckets

  char* ws = (char*)d_ws;
  size_t off = 0;
  unsigned short* featb = (unsigned short*)(ws + off); off += (size_t)n * HD * sizeof(unsigned short);
  float* el    = (float*)(ws + off); off += (size_t)n * NH * sizeof(float);
  float* er    = (float*)(ws + off); off += (size_t)n * NH * sizeof(float);
  float* ee    = (float*)(ws + off); off += 256;
  int* bincnt  = (int*)(ws + off);   off += NBMAX * sizeof(int);
  int* bbase   = (int*)(ws + off);   off += (NBMAX + 1) * sizeof(int);
  int* bnext   = (int*)(ws + off);   off += NBMAX * sizeof(int);
  unsigned* ebuf = (unsigned*)(ws + off); off += (size_t)ne * sizeof(unsigned);

  hipMemsetAsync(bincnt, 0, NBMAX * sizeof(int), stream);

  k_bincnt<<<512, 256, 0, stream>>>(dst, bincnt, ne, nb);
  k_scan_ee<<<1, 256, 0, stream>>>(bincnt, bbase, bnext, nb, ne,
                                   edge_emb, fceW, attn_e, ee);
  k_msplit<<<(ne + CHUNK - 1) / CHUNK, 256, 0, stream>>>(src, dst, etype, bnext, ebuf, ne, nb);
  k1_mfma<<<(n + 63) / 64, 256, 0, stream>>>(x, fcW, attn_l, attn_r, featb,
                                             (float4*)el, (float4*)er, n);
  k_sortagg<<<nb, 256, 0, stream>>>(ebuf, bbase, el, (const float4*)er, ee,
                                    (const uint4*)featb, (float4*)out, n);
}

// Round 11
// 169.833 us; speedup vs baseline: 5.0155x; 1.0523x over previous
//
#include <hip/hip_runtime.h>

#define NH 4
#define HD 64
#define IN_DIM 128
#define NEG_SLOPE 0.2f
#define BN 128          // dst nodes per bucket
#define NBMAX 1024      // max buckets (n <= 131072)
#define CHUNK 4096      // edges per multisplit block
#define EPT (CHUNK/512) // edges per thread in multisplit (512-thread blocks)
#define SBUFSZ 4096     // per-bucket record capacity (mean 2048, sigma ~45)

typedef short bf8 __attribute__((ext_vector_type(8)));   // 8 bf16 in 4 VGPRs
typedef float f4  __attribute__((ext_vector_type(4)));

__device__ inline unsigned short f2bf(float f) {   // RNE fp32 -> bf16
  unsigned u = __float_as_uint(f);
  u += 0x7FFFu + ((u >> 16) & 1u);
  return (unsigned short)(u >> 16);
}

// ---- K1: feat(bf16) = x @ fc_W via MFMA, + el/er per node, + fused bucket histogram ----
__global__ __launch_bounds__(256) void k1_mfma(
    const float* __restrict__ x, const float* __restrict__ fcW,
    const float* __restrict__ attn_l, const float* __restrict__ attn_r,
    unsigned short* __restrict__ featb, float4* __restrict__ el4, float4* __restrict__ er4,
    const int* __restrict__ dst, int* __restrict__ bincnt, int n, int ne, int nb)
{
  __shared__ unsigned short wt[HD][IN_DIM + 8];   // W^T bf16, padded (17.4 KB)
  __shared__ int lc[NBMAX];                       // 4 KB bucket histogram
  for (int idx = threadIdx.x; idx < IN_DIM * HD; idx += 256) {
    int k = idx >> 6, j = idx & 63;
    wt[j][k] = f2bf(fcW[idx]);
  }
  for (int i = threadIdx.x; i < nb; i += 256) lc[i] = 0;
  __syncthreads();

  const int w  = threadIdx.x >> 6;    // wave 0..3
  const int l  = threadIdx.x & 63;
  const int lr = l & 15;
  const int lg = l >> 4;
  const int rowbase = blockIdx.x * 64 + w * 16;

  int arow = rowbase + lr;
  if (arow >= n) arow = n - 1;                     // clamp; stores predicated
  const float* xp = x + (size_t)arow * IN_DIM + lg * 8;

  f4 acc[4] = {};                                  // one per n-tile (= head)
#pragma unroll
  for (int kc = 0; kc < 4; ++kc) {
    float4 a0 = *(const float4*)(xp + kc * 32);
    float4 a1 = *(const float4*)(xp + kc * 32 + 4);
    bf8 af;
    af[0] = (short)f2bf(a0.x); af[1] = (short)f2bf(a0.y);
    af[2] = (short)f2bf(a0.z); af[3] = (short)f2bf(a0.w);
    af[4] = (short)f2bf(a1.x); af[5] = (short)f2bf(a1.y);
    af[6] = (short)f2bf(a1.z); af[7] = (short)f2bf(a1.w);
#pragma unroll
    for (int nt = 0; nt < 4; ++nt) {
      bf8 bfr = *(const bf8*)&wt[nt * 16 + lr][kc * 32 + lg * 8];
      acc[nt] = __builtin_amdgcn_mfma_f32_16x16x32_bf16(af, bfr, acc[nt], 0, 0, 0);
    }
  }

  float al[NH], ar[NH];
#pragma unroll
  for (int h = 0; h < NH; ++h) { al[h] = attn_l[h * 16 + lr]; ar[h] = attn_r[h * 16 + lr]; }

#pragma unroll
  for (int r = 0; r < 4; ++r) {
    int grow = rowbase + lg * 4 + r;
    bool ok = grow < n;
    if (ok) {
#pragma unroll
      for (int nt = 0; nt < 4; ++nt)
        featb[(size_t)grow * HD + nt * 16 + lr] = f2bf(acc[nt][r]);
    }
    float pl[NH], pr[NH];
#pragma unroll
    for (int h = 0; h < NH; ++h) { pl[h] = acc[h][r] * al[h]; pr[h] = acc[h][r] * ar[h]; }
#pragma unroll
    for (int off = 1; off < 16; off <<= 1) {
#pragma unroll
      for (int h = 0; h < NH; ++h) {
        pl[h] += __shfl_xor(pl[h], off);
        pr[h] += __shfl_xor(pr[h], off);
      }
    }
    if (ok && lr == 0) {
      el4[grow] = make_float4(pl[0], pl[1], pl[2], pl[3]);
      er4[grow] = make_float4(pr[0], pr[1], pr[2], pr[3]);
    }
  }

  // fused bucket histogram (bincnt pre-zeroed by memset)
  for (int e = blockIdx.x * 256 + threadIdx.x; e < ne; e += gridDim.x * 256)
    atomicAdd(&lc[dst[e] >> 7], 1);
  __syncthreads();
  for (int i = threadIdx.x; i < nb; i += 256)
    if (lc[i]) atomicAdd(&bincnt[i], lc[i]);
}

// ---- P1: scan bucket counts -> bbase/bnext (single block) + tiny ee fused ----
__global__ __launch_bounds__(256) void k_scan_ee(
    const int* __restrict__ bincnt, int* __restrict__ bbase, int* __restrict__ bnext,
    int nb, int ne,
    const float* __restrict__ edge_emb, const float* __restrict__ fc_e_W,
    const float* __restrict__ attn_e, float* __restrict__ ee)
{
  __shared__ int wsm[4], wbs[4];
  __shared__ float sef[8][128];
  const int t = threadIdx.x;
  int c[4], s = 0;
#pragma unroll
  for (int j = 0; j < 4; ++j) { int b = 4 * t + j; c[j] = (b < nb) ? bincnt[b] : 0; s += c[j]; }
  const int lane = t & 63, wv = t >> 6;
  int inc = s;
#pragma unroll
  for (int off = 1; off < 64; off <<= 1) {
    int v = __shfl_up(inc, off);
    if (lane >= off) inc += v;
  }
  if (lane == 63) wsm[wv] = inc;
  if (t < 128) {
    for (int r = 0; r < 8; ++r) {
      float acc = 0.f;
#pragma unroll
      for (int k = 0; k < 32; ++k) acc = fmaf(edge_emb[r * 32 + k], fc_e_W[k * 128 + t], acc);
      sef[r][t] = acc;
    }
  }
  __syncthreads();
  if (t == 0) { int r = 0; for (int k = 0; k < 4; ++k) { wbs[k] = r; r += wsm[k]; } }
  __syncthreads();
  int ex = wbs[wv] + inc - s;
#pragma unroll
  for (int j = 0; j < 4; ++j) {
    int b = 4 * t + j;
    if (b < nb) { bbase[b] = ex; bnext[b] = ex; }
    ex += c[j];
  }
  if (t == 0) bbase[nb] = ne;
  if (t < 32) {
    int r = t >> 2, h = t & 3;
    float acc = 0.f;
#pragma unroll
    for (int e2 = 0; e2 < 32; ++e2) acc += sef[r][h * 32 + e2] * attn_e[h * 32 + e2];
    ee[r * NH + h] = acc;
  }
}

// ---- P2: multisplit edges into nb contiguous buckets; rec = src|et<<17|dlocal<<20 ----
__global__ __launch_bounds__(512) void k_msplit(
    const int* __restrict__ src, const int* __restrict__ dst, const int* __restrict__ et,
    int* __restrict__ bnext, unsigned* __restrict__ ebuf, int ne, int nb)
{
  __shared__ int scnt[NBMAX], sbase[NBMAX], gbase[NBMAX];   // 12 KB
  __shared__ unsigned sbuf[CHUNK];                           // 16 KB
  __shared__ int wsm[8], wbs[8];
  const int t = threadIdx.x;
  const int base = blockIdx.x * CHUNK;
  for (int i = t; i < nb; i += 512) scnt[i] = 0;
  __syncthreads();
  unsigned pk[EPT], rc[EPT];
#pragma unroll
  for (int i = 0; i < EPT; ++i) {
    int e = base + i * 512 + t;
    pk[i] = 0xFFFFFFFFu;
    if (e < ne) {
      int d = dst[e];
      int bin = d >> 7;
      rc[i] = (unsigned)src[e] | ((unsigned)et[e] << 17) | ((unsigned)(d & 127) << 20);
      int slot = atomicAdd(&scnt[bin], 1);
      pk[i] = (unsigned)slot * 1024u + (unsigned)bin;
    }
  }
  __syncthreads();
  int c[4], s = 0;
#pragma unroll
  for (int j = 0; j < 4; ++j) { int b = 4 * t + j; c[j] = (b < nb) ? scnt[b] : 0; s += c[j]; }
  const int lane = t & 63, wv = t >> 6;
  int inc = s;
#pragma unroll
  for (int off = 1; off < 64; off <<= 1) {
    int v = __shfl_up(inc, off);
    if (lane >= off) inc += v;
  }
  if (lane == 63) wsm[wv] = inc;
  __syncthreads();
  if (t == 0) { int r = 0; for (int k = 0; k < 8; ++k) { wbs[k] = r; r += wsm[k]; } }
  __syncthreads();
  int ex = wbs[wv] + inc - s;
#pragma unroll
  for (int j = 0; j < 4; ++j) {
    int b = 4 * t + j;
    if (b < nb) {
      sbase[b] = ex;
      if (c[j] > 0) gbase[b] = atomicAdd(&bnext[b], c[j]);
    }
    ex += c[j];
  }
  __syncthreads();
#pragma unroll
  for (int i = 0; i < EPT; ++i) {
    if (pk[i] != 0xFFFFFFFFu) {
      int bin = (int)(pk[i] & 1023u);
      int slot = (int)(pk[i] >> 10);
      sbuf[sbase[bin] + slot] = rc[i];
    }
  }
  __syncthreads();
  // copy-out: 8 record-lanes per bin, 64 bins per block-iteration (all lanes active)
  const int sub = lane >> 3, rl = lane & 7;
  for (int b0 = wv * 8 + sub; b0 < nb; b0 += 64) {
    int cnt = scnt[b0];
    if (cnt > 0) {
      int sb = sbase[b0], gb = gbase[b0];
      for (int i2 = rl; i2 < cnt; i2 += 8)
        ebuf[gb + i2] = sbuf[sb + i2];
    }
  }
}

// ---- P3: per-bucket LDS counting sort (reg-cached, one atomic) + register-accum aggregation ----
__global__ __launch_bounds__(512) void k_sortagg(
    const unsigned* __restrict__ ebuf, const int* __restrict__ bbase,
    const float* __restrict__ el, const float4* __restrict__ er4,
    const float* __restrict__ eeg, const uint4* __restrict__ featq,
    float4* __restrict__ out4, int n)
{
  __shared__ unsigned sbuf[SBUFSZ];    // 16 KB
  __shared__ int cnt[BN];              // histogram
  __shared__ int sb[BN + 1];           // segment bases (bucket-local)
  __shared__ float s_er[BN][NH];       // 2 KB
  __shared__ float s_ee[32];
  __shared__ int wsum[2];
  const int t = threadIdx.x;
  const int node0 = blockIdx.x * BN;
  const int beg = bbase[blockIdx.x], end = bbase[blockIdx.x + 1];
  const int count = end - beg;
  for (int i = t; i < BN; i += 512) {
    cnt[i] = 0;
    int node = node0 + i;
    float4 v = (node < n) ? er4[node] : make_float4(0.f, 0.f, 0.f, 0.f);
    s_er[i][0] = v.x; s_er[i][1] = v.y; s_er[i][2] = v.z; s_er[i][3] = v.w;
  }
  if (t < 32) s_ee[t] = eeg[t];
  __syncthreads();

  const int lane = t & 63, wv = t >> 6;
  const int q = lane >> 3;      // 8 records in flight per wave
  const int l = lane & 7;       // dim octet: dims 8l..8l+7
  const int h = l >> 1;         // head for this lane's dims
  const bool sorted = (count <= SBUFSZ);

  if (sorted) {
    // pass 1: histogram; cache record + within-bin slot in registers
    unsigned rr_[SBUFSZ / 512], pk_[SBUFSZ / 512];
#pragma unroll
    for (int j = 0; j < SBUFSZ / 512; ++j) {
      int i = beg + j * 512 + t;
      pk_[j] = 0xFFFFFFFFu;
      if (i < end) {
        unsigned r = ebuf[i];
        rr_[j] = r;
        unsigned bin = r >> 20;
        unsigned slot = (unsigned)atomicAdd(&cnt[bin], 1);
        pk_[j] = (slot << 7) | bin;
      }
    }
    __syncthreads();
    // scan 128 bins with waves 0-1
    int cc = 0, inc = 0;
    if (t < 128) {
      cc = cnt[t];
      inc = cc;
#pragma unroll
      for (int off = 1; off < 64; off <<= 1) {
        int v = __shfl_up(inc, off);
        if (lane >= off) inc += v;
      }
      if (lane == 63) wsum[wv] = inc;
    }
    __syncthreads();
    if (t < 128) {
      int ex = (wv ? wsum[0] : 0) + inc - cc;
      sb[t] = ex;
      if (t == 127) sb[128] = ex + cc;
    }
    __syncthreads();
    // pass 2: place from registers (no atomics, no re-read)
#pragma unroll
    for (int j = 0; j < SBUFSZ / 512; ++j) {
      if (pk_[j] != 0xFFFFFFFFu)
        sbuf[sb[pk_[j] & 127u] + (int)(pk_[j] >> 7)] = rr_[j];
    }
    __syncthreads();
  }

  // aggregation: wave wv owns dsts [wv*16, wv*16+16)
  for (int ld = wv * 16; ld < wv * 16 + 16; ++ld) {
    float erh = s_er[ld][h];
    float a0 = 0.f, a1 = 0.f, a2 = 0.f, a3 = 0.f;
    float a4 = 0.f, a5 = 0.f, a6 = 0.f, a7 = 0.f, den = 0.f;
    if (sorted) {
      const int s0 = sb[ld], s1 = sb[ld + 1];
      for (int i = s0 + q; i < s1; i += 8) {
        unsigned r = sbuf[i];
        int s  = (int)(r & 0x1FFFFu);
        int tt = (int)((r >> 17) & 7u);
        float sv = el[s * NH + h] + erh + s_ee[tt * NH + h];
        sv = sv > 0.f ? sv : NEG_SLOPE * sv;
        float p = __expf(sv);
        den += p;
        uint4 u = featq[(size_t)s * 8 + l];
        a0 = fmaf(p, __uint_as_float(u.x << 16), a0);
        a1 = fmaf(p, __uint_as_float(u.x & 0xFFFF0000u), a1);
        a2 = fmaf(p, __uint_as_float(u.y << 16), a2);
        a3 = fmaf(p, __uint_as_float(u.y & 0xFFFF0000u), a3);
        a4 = fmaf(p, __uint_as_float(u.z << 16), a4);
        a5 = fmaf(p, __uint_as_float(u.z & 0xFFFF0000u), a5);
        a6 = fmaf(p, __uint_as_float(u.w << 16), a6);
        a7 = fmaf(p, __uint_as_float(u.w & 0xFFFF0000u), a7);
      }
    } else {
      // fallback (statistically never): filtered direct scan of the bucket
      for (int i = beg + q; i < end; i += 8) {
        unsigned r = ebuf[i];
        if ((int)(r >> 20) != ld) continue;
        int s  = (int)(r & 0x1FFFFu);
        int tt = (int)((r >> 17) & 7u);
        float sv = el[s * NH + h] + erh + s_ee[tt * NH + h];
        sv = sv > 0.f ? sv : NEG_SLOPE * sv;
        float p = __expf(sv);
        den += p;
        uint4 u = featq[(size_t)s * 8 + l];
        a0 = fmaf(p, __uint_as_float(u.x << 16), a0);
        a1 = fmaf(p, __uint_as_float(u.x & 0xFFFF0000u), a1);
        a2 = fmaf(p, __uint_as_float(u.y << 16), a2);
        a3 = fmaf(p, __uint_as_float(u.y & 0xFFFF0000u), a3);
        a4 = fmaf(p, __uint_as_float(u.z << 16), a4);
        a5 = fmaf(p, __uint_as_float(u.z & 0xFFFF0000u), a5);
        a6 = fmaf(p, __uint_as_float(u.w << 16), a6);
        a7 = fmaf(p, __uint_as_float(u.w & 0xFFFF0000u), a7);
      }
    }
#pragma unroll
    for (int off = 8; off <= 32; off <<= 1) {
      den += __shfl_xor(den, off);
      a0 += __shfl_xor(a0, off); a1 += __shfl_xor(a1, off);
      a2 += __shfl_xor(a2, off); a3 += __shfl_xor(a3, off);
      a4 += __shfl_xor(a4, off); a5 += __shfl_xor(a5, off);
      a6 += __shfl_xor(a6, off); a7 += __shfl_xor(a7, off);
    }
    if (q == 0) {
      int node = node0 + ld;
      if (node < n) {
        float inv = den > 0.f ? 1.f / den : 0.f;
        float4* op = out4 + (size_t)node * 16 + l * 2;
        op[0] = make_float4(a0 * inv, a1 * inv, a2 * inv, a3 * inv);
        op[1] = make_float4(a4 * inv, a5 * inv, a6 * inv, a7 * inv);
      }
    }
  }
}

extern "C" void kernel_launch(void* const* d_in, const int* in_sizes, int n_in,
                              void* d_out, int out_size, void* d_ws, size_t ws_size,
                              hipStream_t stream)
{
  const float* x        = (const float*)d_in[0];
  const int*   src      = (const int*)d_in[1];
  const int*   dst      = (const int*)d_in[2];
  const int*   etype    = (const int*)d_in[3];
  const float* fcW      = (const float*)d_in[4];
  const float* fceW     = (const float*)d_in[5];
  const float* edge_emb = (const float*)d_in[6];
  const float* attn_l   = (const float*)d_in[7];
  const float* attn_r   = (const float*)d_in[8];
  const float* attn_e   = (const float*)d_in[9];
  float* out = (float*)d_out;

  const int n  = in_sizes[0] / IN_DIM;      // 100000
  const int ne = in_sizes[1];               // 1600000
  const int nb = (n + BN - 1) / BN;         // 782 buckets

  char* ws = (char*)d_ws;
  size_t off = 0;
  unsigned short* featb = (unsigned short*)(ws + off); off += (size_t)n * HD * sizeof(unsigned short);
  float* el    = (float*)(ws + off); off += (size_t)n * NH * sizeof(float);
  float* er    = (float*)(ws + off); off += (size_t)n * NH * sizeof(float);
  float* ee    = (float*)(ws + off); off += 256;
  int* bincnt  = (int*)(ws + off);   off += NBMAX * sizeof(int);
  int* bbase   = (int*)(ws + off);   off += (NBMAX + 1) * sizeof(int);
  int* bnext   = (int*)(ws + off);   off += NBMAX * sizeof(int);
  unsigned* ebuf = (unsigned*)(ws + off); off += (size_t)ne * sizeof(unsigned);

  hipMemsetAsync(bincnt, 0, NBMAX * sizeof(int), stream);

  k1_mfma<<<(n + 63) / 64, 256, 0, stream>>>(x, fcW, attn_l, attn_r, featb,
                                             (float4*)el, (float4*)er,
                                             dst, bincnt, n, ne, nb);
  k_scan_ee<<<1, 256, 0, stream>>>(bincnt, bbase, bnext, nb, ne,
                                   edge_emb, fceW, attn_e, ee);
  k_msplit<<<(ne + CHUNK - 1) / CHUNK, 512, 0, stream>>>(src, dst, etype, bnext, ebuf, ne, nb);
  k_sortagg<<<nb, 512, 0, stream>>>(ebuf, bbase, el, (const float4*)er, ee,
                                    (const uint4*)featb, (float4*)out, n);
}

// Round 12
// 164.870 us; speedup vs baseline: 5.1665x; 1.0301x over previous
//
#include <hip/hip_runtime.h>

#define NH 4
#define HD 64
#define IN_DIM 128
#define NEG_SLOPE 0.2f
#define BN 128          // dst nodes per bucket
#define NBMAX 1024      // max buckets (n <= 131072)
#define CHUNK 4096      // edges per multisplit block
#define EPT (CHUNK/512) // edges per thread in multisplit (512-thread blocks)
#define SBUFSZ 4096     // per-bucket record capacity (mean 2048, sigma ~45)
#define HISTB 512       // dedicated histogram blocks appended to k1's grid

typedef short bf8 __attribute__((ext_vector_type(8)));   // 8 bf16 in 4 VGPRs
typedef float f4  __attribute__((ext_vector_type(4)));

__device__ inline unsigned short f2bf(float f) {   // RNE fp32 -> bf16
  unsigned u = __float_as_uint(f);
  u += 0x7FFFu + ((u >> 16) & 1u);
  return (unsigned short)(u >> 16);
}

// ---- K1: feat(bf16) = x @ fc_W via MFMA + el/er; blocks >= nmfma do the bucket histogram ----
__global__ __launch_bounds__(256) void k1_mfma(
    const float* __restrict__ x, const float* __restrict__ fcW,
    const float* __restrict__ attn_l, const float* __restrict__ attn_r,
    unsigned short* __restrict__ featb, float4* __restrict__ el4, float4* __restrict__ er4,
    const int* __restrict__ dst, int* __restrict__ bincnt, int n, int ne, int nb, int nmfma)
{
  if (blockIdx.x >= nmfma) {
    // ---- histogram role (runs concurrently with MFMA blocks) ----
    __shared__ int lc[NBMAX];
    for (int i = threadIdx.x; i < nb; i += 256) lc[i] = 0;
    __syncthreads();
    const int hb = blockIdx.x - nmfma;
    const int HB = gridDim.x - nmfma;
    for (int e = hb * 256 + threadIdx.x; e < ne; e += HB * 256)
      atomicAdd(&lc[dst[e] >> 7], 1);
    __syncthreads();
    for (int i = threadIdx.x; i < nb; i += 256)
      if (lc[i]) atomicAdd(&bincnt[i], lc[i]);
    return;
  }

  __shared__ unsigned short wt[HD][IN_DIM + 8];   // W^T bf16, padded (17.4 KB)
  for (int idx = threadIdx.x; idx < IN_DIM * HD; idx += 256) {
    int k = idx >> 6, j = idx & 63;
    wt[j][k] = f2bf(fcW[idx]);
  }
  __syncthreads();

  const int w  = threadIdx.x >> 6;    // wave 0..3
  const int l  = threadIdx.x & 63;
  const int lr = l & 15;
  const int lg = l >> 4;
  const int rowbase = blockIdx.x * 64 + w * 16;

  int arow = rowbase + lr;
  if (arow >= n) arow = n - 1;                     // clamp; stores predicated
  const float* xp = x + (size_t)arow * IN_DIM + lg * 8;

  f4 acc[4] = {};                                  // one per n-tile (= head)
#pragma unroll
  for (int kc = 0; kc < 4; ++kc) {
    float4 a0 = *(const float4*)(xp + kc * 32);
    float4 a1 = *(const float4*)(xp + kc * 32 + 4);
    bf8 af;
    af[0] = (short)f2bf(a0.x); af[1] = (short)f2bf(a0.y);
    af[2] = (short)f2bf(a0.z); af[3] = (short)f2bf(a0.w);
    af[4] = (short)f2bf(a1.x); af[5] = (short)f2bf(a1.y);
    af[6] = (short)f2bf(a1.z); af[7] = (short)f2bf(a1.w);
#pragma unroll
    for (int nt = 0; nt < 4; ++nt) {
      bf8 bfr = *(const bf8*)&wt[nt * 16 + lr][kc * 32 + lg * 8];
      acc[nt] = __builtin_amdgcn_mfma_f32_16x16x32_bf16(af, bfr, acc[nt], 0, 0, 0);
    }
  }

  float al[NH], ar[NH];
#pragma unroll
  for (int h = 0; h < NH; ++h) { al[h] = attn_l[h * 16 + lr]; ar[h] = attn_r[h * 16 + lr]; }

#pragma unroll
  for (int r = 0; r < 4; ++r) {
    int grow = rowbase + lg * 4 + r;
    bool ok = grow < n;
    if (ok) {
#pragma unroll
      for (int nt = 0; nt < 4; ++nt)
        featb[(size_t)grow * HD + nt * 16 + lr] = f2bf(acc[nt][r]);
    }
    float pl[NH], pr[NH];
#pragma unroll
    for (int h = 0; h < NH; ++h) { pl[h] = acc[h][r] * al[h]; pr[h] = acc[h][r] * ar[h]; }
#pragma unroll
    for (int off = 1; off < 16; off <<= 1) {
#pragma unroll
      for (int h = 0; h < NH; ++h) {
        pl[h] += __shfl_xor(pl[h], off);
        pr[h] += __shfl_xor(pr[h], off);
      }
    }
    if (ok && lr == 0) {
      el4[grow] = make_float4(pl[0], pl[1], pl[2], pl[3]);
      er4[grow] = make_float4(pr[0], pr[1], pr[2], pr[3]);
    }
  }
}

// ---- P1: scan bucket counts -> bbase/bnext (single block) + tiny ee fused ----
__global__ __launch_bounds__(256) void k_scan_ee(
    const int* __restrict__ bincnt, int* __restrict__ bbase, int* __restrict__ bnext,
    int nb, int ne,
    const float* __restrict__ edge_emb, const float* __restrict__ fc_e_W,
    const float* __restrict__ attn_e, float* __restrict__ ee)
{
  __shared__ int wsm[4], wbs[4];
  __shared__ float sef[8][128];
  const int t = threadIdx.x;
  int c[4], s = 0;
#pragma unroll
  for (int j = 0; j < 4; ++j) { int b = 4 * t + j; c[j] = (b < nb) ? bincnt[b] : 0; s += c[j]; }
  const int lane = t & 63, wv = t >> 6;
  int inc = s;
#pragma unroll
  for (int off = 1; off < 64; off <<= 1) {
    int v = __shfl_up(inc, off);
    if (lane >= off) inc += v;
  }
  if (lane == 63) wsm[wv] = inc;
  if (t < 128) {
    for (int r = 0; r < 8; ++r) {
      float acc = 0.f;
#pragma unroll
      for (int k = 0; k < 32; ++k) acc = fmaf(edge_emb[r * 32 + k], fc_e_W[k * 128 + t], acc);
      sef[r][t] = acc;
    }
  }
  __syncthreads();
  if (t == 0) { int r = 0; for (int k = 0; k < 4; ++k) { wbs[k] = r; r += wsm[k]; } }
  __syncthreads();
  int ex = wbs[wv] + inc - s;
#pragma unroll
  for (int j = 0; j < 4; ++j) {
    int b = 4 * t + j;
    if (b < nb) { bbase[b] = ex; bnext[b] = ex; }
    ex += c[j];
  }
  if (t == 0) bbase[nb] = ne;
  if (t < 32) {
    int r = t >> 2, h = t & 3;
    float acc = 0.f;
#pragma unroll
    for (int e2 = 0; e2 < 32; ++e2) acc += sef[r][h * 32 + e2] * attn_e[h * 32 + e2];
    ee[r * NH + h] = acc;
  }
}

// ---- P2: multisplit edges into nb contiguous buckets; rec = src|et<<17|dlocal<<20 ----
__global__ __launch_bounds__(512) void k_msplit(
    const int* __restrict__ src, const int* __restrict__ dst, const int* __restrict__ et,
    int* __restrict__ bnext, unsigned* __restrict__ ebuf, int ne, int nb)
{
  __shared__ int scnt[NBMAX], sbase[NBMAX], gbase[NBMAX];   // 12 KB
  __shared__ unsigned sbuf[CHUNK];                           // 16 KB
  __shared__ int wsm[8], wbs[8];
  const int t = threadIdx.x;
  const int base = blockIdx.x * CHUNK;
  for (int i = t; i < nb; i += 512) scnt[i] = 0;
  __syncthreads();
  unsigned pk[EPT], rc[EPT];
#pragma unroll
  for (int i = 0; i < EPT; ++i) {
    int e = base + i * 512 + t;
    pk[i] = 0xFFFFFFFFu;
    if (e < ne) {
      int d = dst[e];
      int bin = d >> 7;
      rc[i] = (unsigned)src[e] | ((unsigned)et[e] << 17) | ((unsigned)(d & 127) << 20);
      int slot = atomicAdd(&scnt[bin], 1);
      pk[i] = (unsigned)slot * 1024u + (unsigned)bin;
    }
  }
  __syncthreads();
  int c[4], s = 0;
#pragma unroll
  for (int j = 0; j < 4; ++j) { int b = 4 * t + j; c[j] = (b < nb) ? scnt[b] : 0; s += c[j]; }
  const int lane = t & 63, wv = t >> 6;
  int inc = s;
#pragma unroll
  for (int off = 1; off < 64; off <<= 1) {
    int v = __shfl_up(inc, off);
    if (lane >= off) inc += v;
  }
  if (lane == 63) wsm[wv] = inc;
  __syncthreads();
  if (t == 0) { int r = 0; for (int k = 0; k < 8; ++k) { wbs[k] = r; r += wsm[k]; } }
  __syncthreads();
  int ex = wbs[wv] + inc - s;
#pragma unroll
  for (int j = 0; j < 4; ++j) {
    int b = 4 * t + j;
    if (b < nb) {
      sbase[b] = ex;
      if (c[j] > 0) gbase[b] = atomicAdd(&bnext[b], c[j]);
    }
    ex += c[j];
  }
  __syncthreads();
#pragma unroll
  for (int i = 0; i < EPT; ++i) {
    if (pk[i] != 0xFFFFFFFFu) {
      int bin = (int)(pk[i] & 1023u);
      int slot = (int)(pk[i] >> 10);
      sbuf[sbase[bin] + slot] = rc[i];
    }
  }
  __syncthreads();
  // copy-out: 8 record-lanes per bin, 64 bins per block-iteration (all lanes active)
  const int sub = lane >> 3, rl = lane & 7;
  for (int b0 = wv * 8 + sub; b0 < nb; b0 += 64) {
    int cnt = scnt[b0];
    if (cnt > 0) {
      int sb = sbase[b0], gb = gbase[b0];
      for (int i2 = rl; i2 < cnt; i2 += 8)
        ebuf[gb + i2] = sbuf[sb + i2];
    }
  }
}

// ---- P3: per-bucket LDS counting sort + 4-stream register-accum aggregation ----
__global__ __launch_bounds__(512) void k_sortagg(
    const unsigned* __restrict__ ebuf, const int* __restrict__ bbase,
    const float* __restrict__ el, const float4* __restrict__ er4,
    const float* __restrict__ eeg, const uint4* __restrict__ featq,
    float4* __restrict__ out4, int n)
{
  __shared__ unsigned sbuf[SBUFSZ];    // 16 KB
  __shared__ int cnt[BN];              // histogram
  __shared__ int sb[BN + 1];           // segment bases (bucket-local)
  __shared__ float s_er[BN][NH];       // 2 KB
  __shared__ float s_ee[32];
  __shared__ int wsum[2];
  const int t = threadIdx.x;
  const int node0 = blockIdx.x * BN;
  const int beg = bbase[blockIdx.x], end = bbase[blockIdx.x + 1];
  const int count = end - beg;
  for (int i = t; i < BN; i += 512) {
    cnt[i] = 0;
    int node = node0 + i;
    float4 v = (node < n) ? er4[node] : make_float4(0.f, 0.f, 0.f, 0.f);
    s_er[i][0] = v.x; s_er[i][1] = v.y; s_er[i][2] = v.z; s_er[i][3] = v.w;
  }
  if (t < 32) s_ee[t] = eeg[t];
  __syncthreads();

  const int lane = t & 63, wv = t >> 6;
  const int q = lane >> 3;      // 8 record-slots per stream
  const int l = lane & 7;       // dim octet: dims 8l..8l+7
  const int h = l >> 1;         // head for this lane's dims
  const bool sorted = (count <= SBUFSZ);

  if (sorted) {
    // pass 1: histogram; cache record + within-bin slot in registers
    unsigned rr_[SBUFSZ / 512], pk_[SBUFSZ / 512];
#pragma unroll
    for (int j = 0; j < SBUFSZ / 512; ++j) {
      int i = beg + j * 512 + t;
      pk_[j] = 0xFFFFFFFFu;
      if (i < end) {
        unsigned r = ebuf[i];
        rr_[j] = r;
        unsigned bin = r >> 20;
        unsigned slot = (unsigned)atomicAdd(&cnt[bin], 1);
        pk_[j] = (slot << 7) | bin;
      }
    }
    __syncthreads();
    // scan 128 bins with waves 0-1
    int cc = 0, inc = 0;
    if (t < 128) {
      cc = cnt[t];
      inc = cc;
#pragma unroll
      for (int off = 1; off < 64; off <<= 1) {
        int v = __shfl_up(inc, off);
        if (lane >= off) inc += v;
      }
      if (lane == 63) wsum[wv] = inc;
    }
    __syncthreads();
    if (t < 128) {
      int ex = (wv ? wsum[0] : 0) + inc - cc;
      sb[t] = ex;
      if (t == 127) sb[128] = ex + cc;
    }
    __syncthreads();
    // pass 2: place from registers
#pragma unroll
    for (int j = 0; j < SBUFSZ / 512; ++j) {
      if (pk_[j] != 0xFFFFFFFFu)
        sbuf[sb[pk_[j] & 127u] + (int)(pk_[j] >> 7)] = rr_[j];
    }
    __syncthreads();

    // aggregation: wave wv owns dsts [wv*16, wv*16+16), 4 segment-streams in flight
    for (int k0 = 0; k0 < 16; k0 += 4) {
      const int bld = wv * 16 + k0;
      int s1a[4], iia[4];
      float erh_[4];
#pragma unroll
      for (int k = 0; k < 4; ++k) {
        int s0 = sb[bld + k];
        s1a[k] = sb[bld + k + 1];
        iia[k] = s0 + q;
        erh_[k] = s_er[bld + k][h];
      }
      int trips = 0;
#pragma unroll
      for (int k = 0; k < 4; ++k) {
        int tk = (s1a[k] - (iia[k] - q) + 7) >> 3;
        trips = tk > trips ? tk : trips;
      }
      float den[4] = {0.f, 0.f, 0.f, 0.f};
      float acc[4][8] = {};
      for (int it = 0; it < trips; ++it) {
        unsigned rr[4];
#pragma unroll
        for (int k = 0; k < 4; ++k) {
          int idx = iia[k] < s1a[k] ? iia[k] : (count - 1);   // branchless clamp
          rr[k] = sbuf[idx];
        }
        float pv[4];
        uint4 uu[4];
#pragma unroll
        for (int k = 0; k < 4; ++k) {
          int s  = (int)(rr[k] & 0x1FFFFu);
          int tt = (int)((rr[k] >> 17) & 7u);
          uu[k] = featq[(size_t)s * 8 + l];
          float sv = el[s * NH + h] + erh_[k] + s_ee[tt * NH + h];
          sv = sv > 0.f ? sv : NEG_SLOPE * sv;
          float e = __expf(sv);
          pv[k] = (iia[k] < s1a[k]) ? e : 0.f;
          iia[k] += 8;
        }
#pragma unroll
        for (int k = 0; k < 4; ++k) {
          float p = pv[k];
          den[k] += p;
          acc[k][0] = fmaf(p, __uint_as_float(uu[k].x << 16), acc[k][0]);
          acc[k][1] = fmaf(p, __uint_as_float(uu[k].x & 0xFFFF0000u), acc[k][1]);
          acc[k][2] = fmaf(p, __uint_as_float(uu[k].y << 16), acc[k][2]);
          acc[k][3] = fmaf(p, __uint_as_float(uu[k].y & 0xFFFF0000u), acc[k][3]);
          acc[k][4] = fmaf(p, __uint_as_float(uu[k].z << 16), acc[k][4]);
          acc[k][5] = fmaf(p, __uint_as_float(uu[k].z & 0xFFFF0000u), acc[k][5]);
          acc[k][6] = fmaf(p, __uint_as_float(uu[k].w << 16), acc[k][6]);
          acc[k][7] = fmaf(p, __uint_as_float(uu[k].w & 0xFFFF0000u), acc[k][7]);
        }
      }
#pragma unroll
      for (int k = 0; k < 4; ++k) {
        float d = den[k];
        float a0 = acc[k][0], a1 = acc[k][1], a2 = acc[k][2], a3 = acc[k][3];
        float a4 = acc[k][4], a5 = acc[k][5], a6 = acc[k][6], a7 = acc[k][7];
#pragma unroll
        for (int off = 8; off <= 32; off <<= 1) {
          d  += __shfl_xor(d, off);
          a0 += __shfl_xor(a0, off); a1 += __shfl_xor(a1, off);
          a2 += __shfl_xor(a2, off); a3 += __shfl_xor(a3, off);
          a4 += __shfl_xor(a4, off); a5 += __shfl_xor(a5, off);
          a6 += __shfl_xor(a6, off); a7 += __shfl_xor(a7, off);
        }
        if (q == 0) {
          int node = node0 + bld + k;
          if (node < n) {
            float inv = d > 0.f ? 1.f / d : 0.f;
            float4* op = out4 + (size_t)node * 16 + l * 2;
            op[0] = make_float4(a0 * inv, a1 * inv, a2 * inv, a3 * inv);
            op[1] = make_float4(a4 * inv, a5 * inv, a6 * inv, a7 * inv);
          }
        }
      }
    }
    return;
  }

  // fallback (statistically never): filtered direct scan of the bucket
  for (int ld = wv * 16; ld < wv * 16 + 16; ++ld) {
    float erh = s_er[ld][h];
    float a0 = 0.f, a1 = 0.f, a2 = 0.f, a3 = 0.f;
    float a4 = 0.f, a5 = 0.f, a6 = 0.f, a7 = 0.f, den = 0.f;
    for (int i = beg + q; i < end; i += 8) {
      unsigned r = ebuf[i];
      if ((int)(r >> 20) != ld) continue;
      int s  = (int)(r & 0x1FFFFu);
      int tt = (int)((r >> 17) & 7u);
      float sv = el[s * NH + h] + erh + s_ee[tt * NH + h];
      sv = sv > 0.f ? sv : NEG_SLOPE * sv;
      float p = __expf(sv);
      den += p;
      uint4 u = featq[(size_t)s * 8 + l];
      a0 = fmaf(p, __uint_as_float(u.x << 16), a0);
      a1 = fmaf(p, __uint_as_float(u.x & 0xFFFF0000u), a1);
      a2 = fmaf(p, __uint_as_float(u.y << 16), a2);
      a3 = fmaf(p, __uint_as_float(u.y & 0xFFFF0000u), a3);
      a4 = fmaf(p, __uint_as_float(u.z << 16), a4);
      a5 = fmaf(p, __uint_as_float(u.z & 0xFFFF0000u), a5);
      a6 = fmaf(p, __uint_as_float(u.w << 16), a6);
      a7 = fmaf(p, __uint_as_float(u.w & 0xFFFF0000u), a7);
    }
#pragma unroll
    for (int off = 8; off <= 32; off <<= 1) {
      den += __shfl_xor(den, off);
      a0 += __shfl_xor(a0, off); a1 += __shfl_xor(a1, off);
      a2 += __shfl_xor(a2, off); a3 += __shfl_xor(a3, off);
      a4 += __shfl_xor(a4, off); a5 += __shfl_xor(a5, off);
      a6 += __shfl_xor(a6, off); a7 += __shfl_xor(a7, off);
    }
    if (q == 0) {
      int node = node0 + ld;
      if (node < n) {
        float inv = den > 0.f ? 1.f / den : 0.f;
        float4* op = out4 + (size_t)node * 16 + l * 2;
        op[0] = make_float4(a0 * inv, a1 * inv, a2 * inv, a3 * inv);
        op[1] = make_float4(a4 * inv, a5 * inv, a6 * inv, a7 * inv);
      }
    }
  }
}

extern "C" void kernel_launch(void* const* d_in, const int* in_sizes, int n_in,
                              void* d_out, int out_size, void* d_ws, size_t ws_size,
                              hipStream_t stream)
{
  const float* x        = (const float*)d_in[0];
  const int*   src      = (const int*)d_in[1];
  const int*   dst      = (const int*)d_in[2];
  const int*   etype    = (const int*)d_in[3];
  const float* fcW      = (const float*)d_in[4];
  const float* fceW     = (const float*)d_in[5];
  const float* edge_emb = (const float*)d_in[6];
  const float* attn_l   = (const float*)d_in[7];
  const float* attn_r   = (const float*)d_in[8];
  const float* attn_e   = (const float*)d_in[9];
  float* out = (float*)d_out;

  const int n  = in_sizes[0] / IN_DIM;      // 100000
  const int ne = in_sizes[1];               // 1600000
  const int nb = (n + BN - 1) / BN;         // 782 buckets
  const int nmfma = (n + 63) / 64;          // MFMA blocks in k1

  char* ws = (char*)d_ws;
  size_t off = 0;
  unsigned short* featb = (unsigned short*)(ws + off); off += (size_t)n * HD * sizeof(unsigned short);
  float* el    = (float*)(ws + off); off += (size_t)n * NH * sizeof(float);
  float* er    = (float*)(ws + off); off += (size_t)n * NH * sizeof(float);
  float* ee    = (float*)(ws + off); off += 256;
  int* bincnt  = (int*)(ws + off);   off += NBMAX * sizeof(int);
  int* bbase   = (int*)(ws + off);   off += (NBMAX + 1) * sizeof(int);
  int* bnext   = (int*)(ws + off);   off += NBMAX * sizeof(int);
  unsigned* ebuf = (unsigned*)(ws + off); off += (size_t)ne * sizeof(unsigned);

  hipMemsetAsync(bincnt, 0, NBMAX * sizeof(int), stream);

  k1_mfma<<<nmfma + HISTB, 256, 0, stream>>>(x, fcW, attn_l, attn_r, featb,
                                             (float4*)el, (float4*)er,
                                             dst, bincnt, n, ne, nb, nmfma);
  k_scan_ee<<<1, 256, 0, stream>>>(bincnt, bbase, bnext, nb, ne,
                                   edge_emb, fceW, attn_e, ee);
  k_msplit<<<(ne + CHUNK - 1) / CHUNK, 512, 0, stream>>>(src, dst, etype, bnext, ebuf, ne, nb);
  k_sortagg<<<nb, 512, 0, stream>>>(ebuf, bbase, el, (const float4*)er, ee,
                                    (const uint4*)featb, (float4*)out, n);
}

// Round 13
// 153.087 us; speedup vs baseline: 5.5641x; 1.0770x over previous
//
#include <hip/hip_runtime.h>

#define NH 4
#define HD 64
#define IN_DIM 128
#define NEG_SLOPE 0.2f
#define BN 64           // dst nodes per bucket
#define NBMAX 2048      // max buckets (n <= 131072)
#define CHUNK 4096      // edges per multisplit block
#define EPT (CHUNK/512) // edges per thread in multisplit (512-thread blocks)
#define SBUFSZ 2048     // per-bucket record capacity (mean 1024, sigma ~32)
#define HISTB 512       // dedicated histogram blocks appended to k1's grid
#define NMFMA 512       // MFMA role blocks in k1 (grid-stride over tiles)

typedef short bf8 __attribute__((ext_vector_type(8)));   // 8 bf16 in 4 VGPRs
typedef float f4  __attribute__((ext_vector_type(4)));

__device__ inline unsigned short f2bf(float f) {   // RNE fp32 -> bf16
  unsigned u = __float_as_uint(f);
  u += 0x7FFFu + ((u >> 16) & 1u);
  return (unsigned short)(u >> 16);
}

// ---- K1: feat(bf16) = x @ fc_W via MFMA + el/er (grid-stride tiles); blocks >= nmfma do the bucket histogram ----
__global__ __launch_bounds__(256) void k1_mfma(
    const float* __restrict__ x, const float* __restrict__ fcW,
    const float* __restrict__ attn_l, const float* __restrict__ attn_r,
    unsigned short* __restrict__ featb, float4* __restrict__ el4, float4* __restrict__ er4,
    const int* __restrict__ dst, int* __restrict__ bincnt, int n, int ne, int nb, int nmfma)
{
  if (blockIdx.x >= nmfma) {
    // ---- histogram role (runs concurrently with MFMA blocks) ----
    __shared__ int lc[NBMAX];
    for (int i = threadIdx.x; i < nb; i += 256) lc[i] = 0;
    __syncthreads();
    const int hb = blockIdx.x - nmfma;
    const int HB = gridDim.x - nmfma;
    for (int e = hb * 256 + threadIdx.x; e < ne; e += HB * 256)
      atomicAdd(&lc[dst[e] >> 6], 1);
    __syncthreads();
    for (int i = threadIdx.x; i < nb; i += 256)
      if (lc[i]) atomicAdd(&bincnt[i], lc[i]);
    return;
  }

  __shared__ unsigned short wt[HD][IN_DIM + 8];   // W^T bf16, padded (17.4 KB)
  for (int idx = threadIdx.x; idx < IN_DIM * HD; idx += 256) {
    int k = idx >> 6, j = idx & 63;
    wt[j][k] = f2bf(fcW[idx]);
  }
  __syncthreads();

  const int w  = threadIdx.x >> 6;    // wave 0..3
  const int l  = threadIdx.x & 63;
  const int lr = l & 15;
  const int lg = l >> 4;

  float al[NH], ar[NH];
#pragma unroll
  for (int h = 0; h < NH; ++h) { al[h] = attn_l[h * 16 + lr]; ar[h] = attn_r[h * 16 + lr]; }

  const int ntiles = (n + 63) >> 6;
  for (int tile = blockIdx.x; tile < ntiles; tile += nmfma) {
    const int rowbase = tile * 64 + w * 16;
    int arow = rowbase + lr;
    if (arow >= n) arow = n - 1;                   // clamp; stores predicated
    const float* xp = x + (size_t)arow * IN_DIM + lg * 8;

    f4 acc[4] = {};                                // one per n-tile (= head)
#pragma unroll
    for (int kc = 0; kc < 4; ++kc) {
      float4 a0 = *(const float4*)(xp + kc * 32);
      float4 a1 = *(const float4*)(xp + kc * 32 + 4);
      bf8 af;
      af[0] = (short)f2bf(a0.x); af[1] = (short)f2bf(a0.y);
      af[2] = (short)f2bf(a0.z); af[3] = (short)f2bf(a0.w);
      af[4] = (short)f2bf(a1.x); af[5] = (short)f2bf(a1.y);
      af[6] = (short)f2bf(a1.z); af[7] = (short)f2bf(a1.w);
#pragma unroll
      for (int nt = 0; nt < 4; ++nt) {
        bf8 bfr = *(const bf8*)&wt[nt * 16 + lr][kc * 32 + lg * 8];
        acc[nt] = __builtin_amdgcn_mfma_f32_16x16x32_bf16(af, bfr, acc[nt], 0, 0, 0);
      }
    }

#pragma unroll
    for (int r = 0; r < 4; ++r) {
      int grow = rowbase + lg * 4 + r;
      bool ok = grow < n;
      if (ok) {
#pragma unroll
        for (int nt = 0; nt < 4; ++nt)
          featb[(size_t)grow * HD + nt * 16 + lr] = f2bf(acc[nt][r]);
      }
      float pl[NH], pr[NH];
#pragma unroll
      for (int h = 0; h < NH; ++h) { pl[h] = acc[h][r] * al[h]; pr[h] = acc[h][r] * ar[h]; }
#pragma unroll
      for (int off = 1; off < 16; off <<= 1) {
#pragma unroll
        for (int h = 0; h < NH; ++h) {
          pl[h] += __shfl_xor(pl[h], off);
          pr[h] += __shfl_xor(pr[h], off);
        }
      }
      if (ok && lr == 0) {
        el4[grow] = make_float4(pl[0], pl[1], pl[2], pl[3]);
        er4[grow] = make_float4(pr[0], pr[1], pr[2], pr[3]);
      }
    }
  }
}

// ---- P1: scan bucket counts -> bbase/bnext (single block, 8 bins/thread) + tiny ee fused ----
__global__ __launch_bounds__(256) void k_scan_ee(
    const int* __restrict__ bincnt, int* __restrict__ bbase, int* __restrict__ bnext,
    int nb, int ne,
    const float* __restrict__ edge_emb, const float* __restrict__ fc_e_W,
    const float* __restrict__ attn_e, float* __restrict__ ee)
{
  __shared__ int wsm[4], wbs[4];
  __shared__ float sef[8][128];
  const int t = threadIdx.x;
  int c[8], s = 0;
#pragma unroll
  for (int j = 0; j < 8; ++j) { int b = 8 * t + j; c[j] = (b < nb) ? bincnt[b] : 0; s += c[j]; }
  const int lane = t & 63, wv = t >> 6;
  int inc = s;
#pragma unroll
  for (int off = 1; off < 64; off <<= 1) {
    int v = __shfl_up(inc, off);
    if (lane >= off) inc += v;
  }
  if (lane == 63) wsm[wv] = inc;
  if (t < 128) {
    for (int r = 0; r < 8; ++r) {
      float acc = 0.f;
#pragma unroll
      for (int k = 0; k < 32; ++k) acc = fmaf(edge_emb[r * 32 + k], fc_e_W[k * 128 + t], acc);
      sef[r][t] = acc;
    }
  }
  __syncthreads();
  if (t == 0) { int r = 0; for (int k = 0; k < 4; ++k) { wbs[k] = r; r += wsm[k]; } }
  __syncthreads();
  int ex = wbs[wv] + inc - s;
#pragma unroll
  for (int j = 0; j < 8; ++j) {
    int b = 8 * t + j;
    if (b < nb) { bbase[b] = ex; bnext[b] = ex; }
    ex += c[j];
  }
  if (t == 0) bbase[nb] = ne;
  if (t < 32) {
    int r = t >> 2, h = t & 3;
    float acc = 0.f;
#pragma unroll
    for (int e2 = 0; e2 < 32; ++e2) acc += sef[r][h * 32 + e2] * attn_e[h * 32 + e2];
    ee[r * NH + h] = acc;
  }
}

// ---- P2: multisplit edges into nb contiguous buckets; rec = src|et<<17|dlocal<<20 ----
__global__ __launch_bounds__(512) void k_msplit(
    const int* __restrict__ src, const int* __restrict__ dst, const int* __restrict__ et,
    int* __restrict__ bnext, unsigned* __restrict__ ebuf, int ne, int nb)
{
  __shared__ int scnt[NBMAX], sbase[NBMAX], gbase[NBMAX];   // 24 KB
  __shared__ unsigned sbuf[CHUNK];                           // 16 KB
  __shared__ int wsm[8], wbs[8];
  const int t = threadIdx.x;
  const int base = blockIdx.x * CHUNK;
  for (int i = t; i < nb; i += 512) scnt[i] = 0;
  __syncthreads();
  unsigned pk[EPT], rc[EPT];
#pragma unroll
  for (int i = 0; i < EPT; ++i) {
    int e = base + i * 512 + t;
    pk[i] = 0xFFFFFFFFu;
    if (e < ne) {
      int d = dst[e];
      int bin = d >> 6;
      rc[i] = (unsigned)src[e] | ((unsigned)et[e] << 17) | ((unsigned)(d & 63) << 20);
      int slot = atomicAdd(&scnt[bin], 1);
      pk[i] = ((unsigned)slot << 11) | (unsigned)bin;
    }
  }
  __syncthreads();
  int c[4], s = 0;
#pragma unroll
  for (int j = 0; j < 4; ++j) { int b = 4 * t + j; c[j] = (b < nb) ? scnt[b] : 0; s += c[j]; }
  const int lane = t & 63, wv = t >> 6;
  int inc = s;
#pragma unroll
  for (int off = 1; off < 64; off <<= 1) {
    int v = __shfl_up(inc, off);
    if (lane >= off) inc += v;
  }
  if (lane == 63) wsm[wv] = inc;
  __syncthreads();
  if (t == 0) { int r = 0; for (int k = 0; k < 8; ++k) { wbs[k] = r; r += wsm[k]; } }
  __syncthreads();
  int ex = wbs[wv] + inc - s;
#pragma unroll
  for (int j = 0; j < 4; ++j) {
    int b = 4 * t + j;
    if (b < nb) {
      sbase[b] = ex;
      if (c[j] > 0) gbase[b] = atomicAdd(&bnext[b], c[j]);
    }
    ex += c[j];
  }
  __syncthreads();
#pragma unroll
  for (int i = 0; i < EPT; ++i) {
    if (pk[i] != 0xFFFFFFFFu) {
      int bin = (int)(pk[i] & 2047u);
      int slot = (int)(pk[i] >> 11);
      sbuf[sbase[bin] + slot] = rc[i];
    }
  }
  __syncthreads();
  // copy-out: 8 record-lanes per bin, 64 bins per block-iteration (all lanes active)
  const int sub = lane >> 3, rl = lane & 7;
  for (int b0 = wv * 8 + sub; b0 < nb; b0 += 64) {
    int cnt = scnt[b0];
    if (cnt > 0) {
      int sb = sbase[b0], gb = gbase[b0];
      for (int i2 = rl; i2 < cnt; i2 += 8)
        ebuf[gb + i2] = sbuf[sb + i2];
    }
  }
}

// ---- P3: per-bucket LDS counting sort (reg-cached, one atomic) + register-accum aggregation ----
__global__ __launch_bounds__(512) void k_sortagg(
    const unsigned* __restrict__ ebuf, const int* __restrict__ bbase,
    const float* __restrict__ el, const float4* __restrict__ er4,
    const float* __restrict__ eeg, const uint4* __restrict__ featq,
    float4* __restrict__ out4, int n)
{
  __shared__ unsigned sbuf[SBUFSZ];    // 8 KB
  __shared__ int cnt[BN];              // histogram
  __shared__ int sb[BN + 1];           // segment bases (bucket-local)
  __shared__ float s_er[BN][NH];       // 1 KB
  __shared__ float s_ee[32];
  const int t = threadIdx.x;
  const int node0 = blockIdx.x * BN;
  const int beg = bbase[blockIdx.x], end = bbase[blockIdx.x + 1];
  const int count = end - beg;
  for (int i = t; i < BN; i += 512) {
    cnt[i] = 0;
    int node = node0 + i;
    float4 v = (node < n) ? er4[node] : make_float4(0.f, 0.f, 0.f, 0.f);
    s_er[i][0] = v.x; s_er[i][1] = v.y; s_er[i][2] = v.z; s_er[i][3] = v.w;
  }
  if (t < 32) s_ee[t] = eeg[t];
  __syncthreads();

  const int lane = t & 63, wv = t >> 6;
  const int q = lane >> 3;      // 8 records in flight per wave
  const int l = lane & 7;       // dim octet: dims 8l..8l+7
  const int h = l >> 1;         // head for this lane's dims
  const bool sorted = (count <= SBUFSZ);

  if (sorted) {
    // pass 1: histogram; cache record + within-bin slot in registers
    unsigned rr_[SBUFSZ / 512], pk_[SBUFSZ / 512];
#pragma unroll
    for (int j = 0; j < SBUFSZ / 512; ++j) {
      int i = beg + j * 512 + t;
      pk_[j] = 0xFFFFFFFFu;
      if (i < end) {
        unsigned r = ebuf[i];
        rr_[j] = r;
        unsigned bin = r >> 20;
        unsigned slot = (unsigned)atomicAdd(&cnt[bin], 1);
        pk_[j] = (slot << 6) | bin;
      }
    }
    __syncthreads();
    // scan 64 bins with wave 0
    if (t < 64) {
      int cc = cnt[t];
      int inc = cc;
#pragma unroll
      for (int off = 1; off < 64; off <<= 1) {
        int v = __shfl_up(inc, off);
        if (lane >= off) inc += v;
      }
      int ex = inc - cc;
      sb[t] = ex;
      if (t == 63) sb[64] = ex + cc;
    }
    __syncthreads();
    // pass 2: place from registers (no atomics, no re-read)
#pragma unroll
    for (int j = 0; j < SBUFSZ / 512; ++j) {
      if (pk_[j] != 0xFFFFFFFFu)
        sbuf[sb[pk_[j] & 63u] + (int)(pk_[j] >> 6)] = rr_[j];
    }
    __syncthreads();
  }

  // aggregation: wave wv owns dsts [wv*8, wv*8+8)
  for (int ld = wv * 8; ld < wv * 8 + 8; ++ld) {
    float erh = s_er[ld][h];
    float a0 = 0.f, a1 = 0.f, a2 = 0.f, a3 = 0.f;
    float a4 = 0.f, a5 = 0.f, a6 = 0.f, a7 = 0.f, den = 0.f;
    if (sorted) {
      const int s0 = sb[ld], s1 = sb[ld + 1];
      for (int i = s0 + q; i < s1; i += 8) {
        unsigned r = sbuf[i];
        int s  = (int)(r & 0x1FFFFu);
        int tt = (int)((r >> 17) & 7u);
        float sv = el[s * NH + h] + erh + s_ee[tt * NH + h];
        sv = sv > 0.f ? sv : NEG_SLOPE * sv;
        float p = __expf(sv);
        den += p;
        uint4 u = featq[(size_t)s * 8 + l];
        a0 = fmaf(p, __uint_as_float(u.x << 16), a0);
        a1 = fmaf(p, __uint_as_float(u.x & 0xFFFF0000u), a1);
        a2 = fmaf(p, __uint_as_float(u.y << 16), a2);
        a3 = fmaf(p, __uint_as_float(u.y & 0xFFFF0000u), a3);
        a4 = fmaf(p, __uint_as_float(u.z << 16), a4);
        a5 = fmaf(p, __uint_as_float(u.z & 0xFFFF0000u), a5);
        a6 = fmaf(p, __uint_as_float(u.w << 16), a6);
        a7 = fmaf(p, __uint_as_float(u.w & 0xFFFF0000u), a7);
      }
    } else {
      // fallback (statistically never): filtered direct scan of the bucket
      for (int i = beg + q; i < end; i += 8) {
        unsigned r = ebuf[i];
        if ((int)(r >> 20) != ld) continue;
        int s  = (int)(r & 0x1FFFFu);
        int tt = (int)((r >> 17) & 7u);
        float sv = el[s * NH + h] + erh + s_ee[tt * NH + h];
        sv = sv > 0.f ? sv : NEG_SLOPE * sv;
        float p = __expf(sv);
        den += p;
        uint4 u = featq[(size_t)s * 8 + l];
        a0 = fmaf(p, __uint_as_float(u.x << 16), a0);
        a1 = fmaf(p, __uint_as_float(u.x & 0xFFFF0000u), a1);
        a2 = fmaf(p, __uint_as_float(u.y << 16), a2);
        a3 = fmaf(p, __uint_as_float(u.y & 0xFFFF0000u), a3);
        a4 = fmaf(p, __uint_as_float(u.z << 16), a4);
        a5 = fmaf(p, __uint_as_float(u.z & 0xFFFF0000u), a5);
        a6 = fmaf(p, __uint_as_float(u.w << 16), a6);
        a7 = fmaf(p, __uint_as_float(u.w & 0xFFFF0000u), a7);
      }
    }
#pragma unroll
    for (int off = 8; off <= 32; off <<= 1) {
      den += __shfl_xor(den, off);
      a0 += __shfl_xor(a0, off); a1 += __shfl_xor(a1, off);
      a2 += __shfl_xor(a2, off); a3 += __shfl_xor(a3, off);
      a4 += __shfl_xor(a4, off); a5 += __shfl_xor(a5, off);
      a6 += __shfl_xor(a6, off); a7 += __shfl_xor(a7, off);
    }
    if (q == 0) {
      int node = node0 + ld;
      if (node < n) {
        float inv = den > 0.f ? 1.f / den : 0.f;
        float4* op = out4 + (size_t)node * 16 + l * 2;
        op[0] = make_float4(a0 * inv, a1 * inv, a2 * inv, a3 * inv);
        op[1] = make_float4(a4 * inv, a5 * inv, a6 * inv, a7 * inv);
      }
    }
  }
}

extern "C" void kernel_launch(void* const* d_in, const int* in_sizes, int n_in,
                              void* d_out, int out_size, void* d_ws, size_t ws_size,
                              hipStream_t stream)
{
  const float* x        = (const float*)d_in[0];
  const int*   src      = (const int*)d_in[1];
  const int*   dst      = (const int*)d_in[2];
  const int*   etype    = (const int*)d_in[3];
  const float* fcW      = (const float*)d_in[4];
  const float* fceW     = (const float*)d_in[5];
  const float* edge_emb = (const float*)d_in[6];
  const float* attn_l   = (const float*)d_in[7];
  const float* attn_r   = (const float*)d_in[8];
  const float* attn_e   = (const float*)d_in[9];
  float* out = (float*)d_out;

  const int n  = in_sizes[0] / IN_DIM;      // 100000
  const int ne = in_sizes[1];               // 1600000
  const int nb = (n + BN - 1) / BN;         // 1563 buckets

  char* ws = (char*)d_ws;
  size_t off = 0;
  unsigned short* featb = (unsigned short*)(ws + off); off += (size_t)n * HD * sizeof(unsigned short);
  float* el    = (float*)(ws + off); off += (size_t)n * NH * sizeof(float);
  float* er    = (float*)(ws + off); off += (size_t)n * NH * sizeof(float);
  float* ee    = (float*)(ws + off); off += 256;
  int* bincnt  = (int*)(ws + off);   off += NBMAX * sizeof(int);
  int* bbase   = (int*)(ws + off);   off += (NBMAX + 1) * sizeof(int);
  int* bnext   = (int*)(ws + off);   off += NBMAX * sizeof(int);
  unsigned* ebuf = (unsigned*)(ws + off); off += (size_t)ne * sizeof(unsigned);

  hipMemsetAsync(bincnt, 0, NBMAX * sizeof(int), stream);

  k1_mfma<<<NMFMA + HISTB, 256, 0, stream>>>(x, fcW, attn_l, attn_r, featb,
                                             (float4*)el, (float4*)er,
                                             dst, bincnt, n, ne, nb, NMFMA);
  k_scan_ee<<<1, 256, 0, stream>>>(bincnt, bbase, bnext, nb, ne,
                                   edge_emb, fceW, attn_e, ee);
  k_msplit<<<(ne + CHUNK - 1) / CHUNK, 512, 0, stream>>>(src, dst, etype, bnext, ebuf, ne, nb);
  k_sortagg<<<nb, 512, 0, stream>>>(ebuf, bbase, el, (const float4*)er, ee,
                                    (const uint4*)featb, (float4*)out, n);
}

// Round 14
// 147.744 us; speedup vs baseline: 5.7653x; 1.0362x over previous
//
#include <hip/hip_runtime.h>

#define NH 4
#define HD 64
#define IN_DIM 128
#define NEG_SLOPE 0.2f
#define BN 64           // dst nodes per bucket
#define NBMAX 2048      // max buckets (n <= 131072)
#define CHUNK 4096      // edges per multisplit block
#define EPT (CHUNK/512) // edges per thread in multisplit (512-thread blocks)
#define SBUFSZ 2048     // per-bucket record capacity (mean 1024, sigma ~32)
#define HISTB 512       // histogram blocks
#define NGEMM 256       // GEMM role blocks in k_combo (grid-stride over tile pairs)

typedef short bf8 __attribute__((ext_vector_type(8)));   // 8 bf16 in 4 VGPRs
typedef float f4  __attribute__((ext_vector_type(4)));

__device__ inline unsigned short f2bf(float f) {   // RNE fp32 -> bf16
  unsigned u = __float_as_uint(f);
  u += 0x7FFFu + ((u >> 16) & 1u);
  return (unsigned short)(u >> 16);
}

// ---- P0: bucket histogram (bin = dst>>6), dedicated kernel ----
__global__ __launch_bounds__(256) void k_hist(
    const int* __restrict__ dst, int* __restrict__ bincnt, int ne, int nb)
{
  __shared__ int lc[NBMAX];
  for (int i = threadIdx.x; i < nb; i += 256) lc[i] = 0;
  __syncthreads();
  for (int e = blockIdx.x * 256 + threadIdx.x; e < ne; e += gridDim.x * 256)
    atomicAdd(&lc[dst[e] >> 6], 1);
  __syncthreads();
  for (int i = threadIdx.x; i < nb; i += 256)
    if (lc[i]) atomicAdd(&bincnt[i], lc[i]);
}

// ---- P1: scan bucket counts -> bbase/bnext (single block, 8 bins/thread) + tiny ee fused ----
__global__ __launch_bounds__(256) void k_scan_ee(
    const int* __restrict__ bincnt, int* __restrict__ bbase, int* __restrict__ bnext,
    int nb, int ne,
    const float* __restrict__ edge_emb, const float* __restrict__ fc_e_W,
    const float* __restrict__ attn_e, float* __restrict__ ee)
{
  __shared__ int wsm[4], wbs[4];
  __shared__ float sef[8][128];
  const int t = threadIdx.x;
  int c[8], s = 0;
#pragma unroll
  for (int j = 0; j < 8; ++j) { int b = 8 * t + j; c[j] = (b < nb) ? bincnt[b] : 0; s += c[j]; }
  const int lane = t & 63, wv = t >> 6;
  int inc = s;
#pragma unroll
  for (int off = 1; off < 64; off <<= 1) {
    int v = __shfl_up(inc, off);
    if (lane >= off) inc += v;
  }
  if (lane == 63) wsm[wv] = inc;
  if (t < 128) {
    for (int r = 0; r < 8; ++r) {
      float acc = 0.f;
#pragma unroll
      for (int k = 0; k < 32; ++k) acc = fmaf(edge_emb[r * 32 + k], fc_e_W[k * 128 + t], acc);
      sef[r][t] = acc;
    }
  }
  __syncthreads();
  if (t == 0) { int r = 0; for (int k = 0; k < 4; ++k) { wbs[k] = r; r += wsm[k]; } }
  __syncthreads();
  int ex = wbs[wv] + inc - s;
#pragma unroll
  for (int j = 0; j < 8; ++j) {
    int b = 8 * t + j;
    if (b < nb) { bbase[b] = ex; bnext[b] = ex; }
    ex += c[j];
  }
  if (t == 0) bbase[nb] = ne;
  if (t < 32) {
    int r = t >> 2, h = t & 3;
    float acc = 0.f;
#pragma unroll
    for (int e2 = 0; e2 < 32; ++e2) acc += sef[r][h * 32 + e2] * attn_e[h * 32 + e2];
    ee[r * NH + h] = acc;
  }
}

// ---- P2: combined dispatch — blocks [0,ngemm) do MFMA projection; the rest do multisplit.
// The two roles use different pipes (MFMA/LDS-read vs LDS-atomic/global), so they overlap.
__global__ __launch_bounds__(512) void k_combo(
    const float* __restrict__ x, const float* __restrict__ fcW,
    const float* __restrict__ attn_l, const float* __restrict__ attn_r,
    unsigned short* __restrict__ featb, float4* __restrict__ el4, float4* __restrict__ er4,
    const int* __restrict__ src, const int* __restrict__ dst, const int* __restrict__ et,
    int* __restrict__ bnext, unsigned* __restrict__ ebuf,
    int n, int ne, int nb, int ngemm)
{
  __shared__ union {
    struct {
      int scnt[NBMAX], sbase[NBMAX], gbase[NBMAX];   // 24 KB
      unsigned sbuf[CHUNK];                          // 16 KB
      int wsm[8], wbs[8];
    } m;
    unsigned short wt[HD][IN_DIM + 8];               // 17.4 KB (GEMM role)
  } sm;

  const int t = threadIdx.x;
  const int lane = t & 63, wv = t >> 6;

  if (blockIdx.x < ngemm) {
    // ======== GEMM role: feat(bf16) = x @ fc_W + el/er; 8 waves = 128 rows/iter ========
    for (int idx = t; idx < IN_DIM * HD; idx += 512) {
      int k = idx >> 6, j = idx & 63;
      sm.wt[j][k] = f2bf(fcW[idx]);
    }
    __syncthreads();

    const int lr = lane & 15;
    const int lg = lane >> 4;
    float al[NH], ar[NH];
#pragma unroll
    for (int h = 0; h < NH; ++h) { al[h] = attn_l[h * 16 + lr]; ar[h] = attn_r[h * 16 + lr]; }

    const int ntp = (n + 127) >> 7;     // tile pairs of 128 rows
    for (int tp = blockIdx.x; tp < ntp; tp += ngemm) {
      const int rowbase = tp * 128 + wv * 16;
      int arow = rowbase + lr;
      if (arow >= n) arow = n - 1;                   // clamp; stores predicated
      const float* xp = x + (size_t)arow * IN_DIM + lg * 8;

      f4 acc[4] = {};                                // one per n-tile (= head)
#pragma unroll
      for (int kc = 0; kc < 4; ++kc) {
        float4 a0 = *(const float4*)(xp + kc * 32);
        float4 a1 = *(const float4*)(xp + kc * 32 + 4);
        bf8 af;
        af[0] = (short)f2bf(a0.x); af[1] = (short)f2bf(a0.y);
        af[2] = (short)f2bf(a0.z); af[3] = (short)f2bf(a0.w);
        af[4] = (short)f2bf(a1.x); af[5] = (short)f2bf(a1.y);
        af[6] = (short)f2bf(a1.z); af[7] = (short)f2bf(a1.w);
#pragma unroll
        for (int nt = 0; nt < 4; ++nt) {
          bf8 bfr = *(const bf8*)&sm.wt[nt * 16 + lr][kc * 32 + lg * 8];
          acc[nt] = __builtin_amdgcn_mfma_f32_16x16x32_bf16(af, bfr, acc[nt], 0, 0, 0);
        }
      }

#pragma unroll
      for (int r = 0; r < 4; ++r) {
        int grow = rowbase + lg * 4 + r;
        bool ok = grow < n;
        if (ok) {
#pragma unroll
          for (int nt = 0; nt < 4; ++nt)
            featb[(size_t)grow * HD + nt * 16 + lr] = f2bf(acc[nt][r]);
        }
        float pl[NH], pr[NH];
#pragma unroll
        for (int h = 0; h < NH; ++h) { pl[h] = acc[h][r] * al[h]; pr[h] = acc[h][r] * ar[h]; }
#pragma unroll
        for (int off = 1; off < 16; off <<= 1) {
#pragma unroll
          for (int h = 0; h < NH; ++h) {
            pl[h] += __shfl_xor(pl[h], off);
            pr[h] += __shfl_xor(pr[h], off);
          }
        }
        if (ok && lr == 0) {
          el4[grow] = make_float4(pl[0], pl[1], pl[2], pl[3]);
          er4[grow] = make_float4(pr[0], pr[1], pr[2], pr[3]);
        }
      }
    }
    return;
  }

  // ======== multisplit role: rec = src|et<<17|dlocal<<20 into nb contiguous buckets ========
  const int base = (blockIdx.x - ngemm) * CHUNK;
  for (int i = t; i < nb; i += 512) sm.m.scnt[i] = 0;
  __syncthreads();
  unsigned pk[EPT], rc[EPT];
#pragma unroll
  for (int i = 0; i < EPT; ++i) {
    int e = base + i * 512 + t;
    pk[i] = 0xFFFFFFFFu;
    if (e < ne) {
      int d = dst[e];
      int bin = d >> 6;
      rc[i] = (unsigned)src[e] | ((unsigned)et[e] << 17) | ((unsigned)(d & 63) << 20);
      int slot = atomicAdd(&sm.m.scnt[bin], 1);
      pk[i] = ((unsigned)slot << 11) | (unsigned)bin;
    }
  }
  __syncthreads();
  int c[4], s = 0;
#pragma unroll
  for (int j = 0; j < 4; ++j) { int b = 4 * t + j; c[j] = (b < nb) ? sm.m.scnt[b] : 0; s += c[j]; }
  int inc = s;
#pragma unroll
  for (int off = 1; off < 64; off <<= 1) {
    int v = __shfl_up(inc, off);
    if (lane >= off) inc += v;
  }
  if (lane == 63) sm.m.wsm[wv] = inc;
  __syncthreads();
  if (t == 0) { int r = 0; for (int k = 0; k < 8; ++k) { sm.m.wbs[k] = r; r += sm.m.wsm[k]; } }
  __syncthreads();
  int ex = sm.m.wbs[wv] + inc - s;
#pragma unroll
  for (int j = 0; j < 4; ++j) {
    int b = 4 * t + j;
    if (b < nb) {
      sm.m.sbase[b] = ex;
      if (c[j] > 0) sm.m.gbase[b] = atomicAdd(&bnext[b], c[j]);
    }
    ex += c[j];
  }
  __syncthreads();
#pragma unroll
  for (int i = 0; i < EPT; ++i) {
    if (pk[i] != 0xFFFFFFFFu) {
      int bin = (int)(pk[i] & 2047u);
      int slot = (int)(pk[i] >> 11);
      sm.m.sbuf[sm.m.sbase[bin] + slot] = rc[i];
    }
  }
  __syncthreads();
  // copy-out: 8 record-lanes per bin, 64 bins per block-iteration (all lanes active)
  const int sub = lane >> 3, rl = lane & 7;
  for (int b0 = wv * 8 + sub; b0 < nb; b0 += 64) {
    int cnt = sm.m.scnt[b0];
    if (cnt > 0) {
      int sb = sm.m.sbase[b0], gb = sm.m.gbase[b0];
      for (int i2 = rl; i2 < cnt; i2 += 8)
        ebuf[gb + i2] = sm.m.sbuf[sb + i2];
    }
  }
}

// ---- P3: per-bucket LDS counting sort (reg-cached, one atomic) + register-accum aggregation ----
__global__ __launch_bounds__(512) void k_sortagg(
    const unsigned* __restrict__ ebuf, const int* __restrict__ bbase,
    const float* __restrict__ el, const float4* __restrict__ er4,
    const float* __restrict__ eeg, const uint4* __restrict__ featq,
    float4* __restrict__ out4, int n)
{
  __shared__ unsigned sbuf[SBUFSZ];    // 8 KB
  __shared__ int cnt[BN];              // histogram
  __shared__ int sb[BN + 1];           // segment bases (bucket-local)
  __shared__ float s_er[BN][NH];       // 1 KB
  __shared__ float s_ee[32];
  const int t = threadIdx.x;
  const int node0 = blockIdx.x * BN;
  const int beg = bbase[blockIdx.x], end = bbase[blockIdx.x + 1];
  const int count = end - beg;
  for (int i = t; i < BN; i += 512) {
    cnt[i] = 0;
    int node = node0 + i;
    float4 v = (node < n) ? er4[node] : make_float4(0.f, 0.f, 0.f, 0.f);
    s_er[i][0] = v.x; s_er[i][1] = v.y; s_er[i][2] = v.z; s_er[i][3] = v.w;
  }
  if (t < 32) s_ee[t] = eeg[t];
  __syncthreads();

  const int lane = t & 63, wv = t >> 6;
  const int q = lane >> 3;      // 8 records in flight per wave
  const int l = lane & 7;       // dim octet: dims 8l..8l+7
  const int h = l >> 1;         // head for this lane's dims
  const bool sorted = (count <= SBUFSZ);

  if (sorted) {
    // pass 1: histogram; cache record + within-bin slot in registers
    unsigned rr_[SBUFSZ / 512], pk_[SBUFSZ / 512];
#pragma unroll
    for (int j = 0; j < SBUFSZ / 512; ++j) {
      int i = beg + j * 512 + t;
      pk_[j] = 0xFFFFFFFFu;
      if (i < end) {
        unsigned r = ebuf[i];
        rr_[j] = r;
        unsigned bin = r >> 20;
        unsigned slot = (unsigned)atomicAdd(&cnt[bin], 1);
        pk_[j] = (slot << 6) | bin;
      }
    }
    __syncthreads();
    // scan 64 bins with wave 0
    if (t < 64) {
      int cc = cnt[t];
      int inc = cc;
#pragma unroll
      for (int off = 1; off < 64; off <<= 1) {
        int v = __shfl_up(inc, off);
        if (lane >= off) inc += v;
      }
      int ex = inc - cc;
      sb[t] = ex;
      if (t == 63) sb[64] = ex + cc;
    }
    __syncthreads();
    // pass 2: place from registers (no atomics, no re-read)
#pragma unroll
    for (int j = 0; j < SBUFSZ / 512; ++j) {
      if (pk_[j] != 0xFFFFFFFFu)
        sbuf[sb[pk_[j] & 63u] + (int)(pk_[j] >> 6)] = rr_[j];
    }
    __syncthreads();
  }

  // aggregation: wave wv owns dsts [wv*8, wv*8+8)
  for (int ld = wv * 8; ld < wv * 8 + 8; ++ld) {
    float erh = s_er[ld][h];
    float a0 = 0.f, a1 = 0.f, a2 = 0.f, a3 = 0.f;
    float a4 = 0.f, a5 = 0.f, a6 = 0.f, a7 = 0.f, den = 0.f;
    if (sorted) {
      const int s0 = sb[ld], s1 = sb[ld + 1];
      for (int i = s0 + q; i < s1; i += 8) {
        unsigned r = sbuf[i];
        int s  = (int)(r & 0x1FFFFu);
        int tt = (int)((r >> 17) & 7u);
        float sv = el[s * NH + h] + erh + s_ee[tt * NH + h];
        sv = sv > 0.f ? sv : NEG_SLOPE * sv;
        float p = __expf(sv);
        den += p;
        uint4 u = featq[(size_t)s * 8 + l];
        a0 = fmaf(p, __uint_as_float(u.x << 16), a0);
        a1 = fmaf(p, __uint_as_float(u.x & 0xFFFF0000u), a1);
        a2 = fmaf(p, __uint_as_float(u.y << 16), a2);
        a3 = fmaf(p, __uint_as_float(u.y & 0xFFFF0000u), a3);
        a4 = fmaf(p, __uint_as_float(u.z << 16), a4);
        a5 = fmaf(p, __uint_as_float(u.z & 0xFFFF0000u), a5);
        a6 = fmaf(p, __uint_as_float(u.w << 16), a6);
        a7 = fmaf(p, __uint_as_float(u.w & 0xFFFF0000u), a7);
      }
    } else {
      // fallback (statistically never): filtered direct scan of the bucket
      for (int i = beg + q; i < end; i += 8) {
        unsigned r = ebuf[i];
        if ((int)(r >> 20) != ld) continue;
        int s  = (int)(r & 0x1FFFFu);
        int tt = (int)((r >> 17) & 7u);
        float sv = el[s * NH + h] + erh + s_ee[tt * NH + h];
        sv = sv > 0.f ? sv : NEG_SLOPE * sv;
        float p = __expf(sv);
        den += p;
        uint4 u = featq[(size_t)s * 8 + l];
        a0 = fmaf(p, __uint_as_float(u.x << 16), a0);
        a1 = fmaf(p, __uint_as_float(u.x & 0xFFFF0000u), a1);
        a2 = fmaf(p, __uint_as_float(u.y << 16), a2);
        a3 = fmaf(p, __uint_as_float(u.y & 0xFFFF0000u), a3);
        a4 = fmaf(p, __uint_as_float(u.z << 16), a4);
        a5 = fmaf(p, __uint_as_float(u.z & 0xFFFF0000u), a5);
        a6 = fmaf(p, __uint_as_float(u.w << 16), a6);
        a7 = fmaf(p, __uint_as_float(u.w & 0xFFFF0000u), a7);
      }
    }
#pragma unroll
    for (int off = 8; off <= 32; off <<= 1) {
      den += __shfl_xor(den, off);
      a0 += __shfl_xor(a0, off); a1 += __shfl_xor(a1, off);
      a2 += __shfl_xor(a2, off); a3 += __shfl_xor(a3, off);
      a4 += __shfl_xor(a4, off); a5 += __shfl_xor(a5, off);
      a6 += __shfl_xor(a6, off); a7 += __shfl_xor(a7, off);
    }
    if (q == 0) {
      int node = node0 + ld;
      if (node < n) {
        float inv = den > 0.f ? 1.f / den : 0.f;
        float4* op = out4 + (size_t)node * 16 + l * 2;
        op[0] = make_float4(a0 * inv, a1 * inv, a2 * inv, a3 * inv);
        op[1] = make_float4(a4 * inv, a5 * inv, a6 * inv, a7 * inv);
      }
    }
  }
}

extern "C" void kernel_launch(void* const* d_in, const int* in_sizes, int n_in,
                              void* d_out, int out_size, void* d_ws, size_t ws_size,
                              hipStream_t stream)
{
  const float* x        = (const float*)d_in[0];
  const int*   src      = (const int*)d_in[1];
  const int*   dst      = (const int*)d_in[2];
  const int*   etype    = (const int*)d_in[3];
  const float* fcW      = (const float*)d_in[4];
  const float* fceW     = (const float*)d_in[5];
  const float* edge_emb = (const float*)d_in[6];
  const float* attn_l   = (const float*)d_in[7];
  const float* attn_r   = (const float*)d_in[8];
  const float* attn_e   = (const float*)d_in[9];
  float* out = (float*)d_out;

  const int n  = in_sizes[0] / IN_DIM;      // 100000
  const int ne = in_sizes[1];               // 1600000
  const int nb = (n + BN - 1) / BN;         // 1563 buckets
  const int nchunks = (ne + CHUNK - 1) / CHUNK;   // 391 multisplit blocks

  char* ws = (char*)d_ws;
  size_t off = 0;
  unsigned short* featb = (unsigned short*)(ws + off); off += (size_t)n * HD * sizeof(unsigned short);
  float* el    = (float*)(ws + off); off += (size_t)n * NH * sizeof(float);
  float* er    = (float*)(ws + off); off += (size_t)n * NH * sizeof(float);
  float* ee    = (float*)(ws + off); off += 256;
  int* bincnt  = (int*)(ws + off);   off += NBMAX * sizeof(int);
  int* bbase   = (int*)(ws + off);   off += (NBMAX + 1) * sizeof(int);
  int* bnext   = (int*)(ws + off);   off += NBMAX * sizeof(int);
  unsigned* ebuf = (unsigned*)(ws + off); off += (size_t)ne * sizeof(unsigned);

  hipMemsetAsync(bincnt, 0, NBMAX * sizeof(int), stream);

  k_hist<<<HISTB, 256, 0, stream>>>(dst, bincnt, ne, nb);
  k_scan_ee<<<1, 256, 0, stream>>>(bincnt, bbase, bnext, nb, ne,
                                   edge_emb, fceW, attn_e, ee);
  k_combo<<<NGEMM + nchunks, 512, 0, stream>>>(x, fcW, attn_l, attn_r, featb,
                                               (float4*)el, (float4*)er,
                                               src, dst, etype, bnext, ebuf,
                                               n, ne, nb, NGEMM);
  k_sortagg<<<nb, 512, 0, stream>>>(ebuf, bbase, el, (const float4*)er, ee,
                                    (const uint4*)featb, (float4*)out, n);
}

// Round 15
// 114.778 us; speedup vs baseline: 7.4212x; 1.2872x over previous
//
#include <hip/hip_runtime.h>

#define NH 4
#define HD 64
#define IN_DIM 128
#define NEG_SLOPE 0.2f
#define BN 64           // dst nodes per bucket
#define NBMAX 1664      // max buckets (n <= 106496)
#define SLAB 2048       // records per bucket slab (mean 1024, sigma ~32)
#define CHUNK 4096      // edges per multisplit block
#define EPT (CHUNK/512) // edges per thread in multisplit (512-thread blocks)
#define SBUFSZ 2048     // sortagg sort capacity (== SLAB)
#define NGEMM 256       // GEMM role blocks in k_combo

typedef short bf8 __attribute__((ext_vector_type(8)));   // 8 bf16 in 4 VGPRs
typedef float f4  __attribute__((ext_vector_type(4)));

__device__ inline unsigned short f2bf(float f) {   // RNE fp32 -> bf16
  unsigned u = __float_as_uint(f);
  u += 0x7FFFu + ((u >> 16) & 1u);
  return (unsigned short)(u >> 16);
}

// ---- P1: combined dispatch. Roles by blockIdx:
//   [0, ngemm)            : MFMA projection feat/el/er
//   [ngemm, ngemm+nchunks): multisplit into fixed-capacity bucket slabs
//   ngemm+nchunks         : tiny ee[t][h] table
// Different pipes (MFMA/LDS-read vs LDS-atomic/global) -> roles overlap on CUs.
__global__ __launch_bounds__(512) void k_combo(
    const float* __restrict__ x, const float* __restrict__ fcW,
    const float* __restrict__ attn_l, const float* __restrict__ attn_r,
    unsigned short* __restrict__ featb, float4* __restrict__ el4, float4* __restrict__ er4,
    const int* __restrict__ src, const int* __restrict__ dst, const int* __restrict__ et,
    int* __restrict__ cntg, unsigned* __restrict__ ebuf,
    const float* __restrict__ edge_emb, const float* __restrict__ fc_e_W,
    const float* __restrict__ attn_e, float* __restrict__ ee,
    int n, int ne, int nb, int ngemm, int nchunks)
{
  __shared__ union {
    struct {
      int scnt[NBMAX];                 // 6.5 KB (int for LDS atomics)
      unsigned short sbase[NBMAX];     // 3.25 KB
      unsigned short goff[NBMAX];      // 3.25 KB (slab offset, clamped <= SLAB)
      unsigned sbuf[CHUNK];            // 16 KB
      int wsm[8], wbs[8];
    } m;
    unsigned short wt[HD][IN_DIM + 8]; // 17.4 KB (GEMM role)
    float sef[8][128];                 // 4 KB (ee role)
  } sm;

  const int t = threadIdx.x;
  const int lane = t & 63, wv = t >> 6;

  if (blockIdx.x < ngemm) {
    // ======== GEMM role: feat(bf16) = x @ fc_W + el/er; 8 waves = 128 rows/iter ========
    for (int idx = t; idx < IN_DIM * HD; idx += 512) {
      int k = idx >> 6, j = idx & 63;
      sm.wt[j][k] = f2bf(fcW[idx]);
    }
    __syncthreads();

    const int lr = lane & 15;
    const int lg = lane >> 4;
    float al[NH], ar[NH];
#pragma unroll
    for (int h = 0; h < NH; ++h) { al[h] = attn_l[h * 16 + lr]; ar[h] = attn_r[h * 16 + lr]; }

    const int ntp = (n + 127) >> 7;     // tile pairs of 128 rows
    for (int tp = blockIdx.x; tp < ntp; tp += ngemm) {
      const int rowbase = tp * 128 + wv * 16;
      int arow = rowbase + lr;
      if (arow >= n) arow = n - 1;                   // clamp; stores predicated
      const float* xp = x + (size_t)arow * IN_DIM + lg * 8;

      f4 acc[4] = {};                                // one per n-tile (= head)
#pragma unroll
      for (int kc = 0; kc < 4; ++kc) {
        float4 a0 = *(const float4*)(xp + kc * 32);
        float4 a1 = *(const float4*)(xp + kc * 32 + 4);
        bf8 af;
        af[0] = (short)f2bf(a0.x); af[1] = (short)f2bf(a0.y);
        af[2] = (short)f2bf(a0.z); af[3] = (short)f2bf(a0.w);
        af[4] = (short)f2bf(a1.x); af[5] = (short)f2bf(a1.y);
        af[6] = (short)f2bf(a1.z); af[7] = (short)f2bf(a1.w);
#pragma unroll
        for (int nt = 0; nt < 4; ++nt) {
          bf8 bfr = *(const bf8*)&sm.wt[nt * 16 + lr][kc * 32 + lg * 8];
          acc[nt] = __builtin_amdgcn_mfma_f32_16x16x32_bf16(af, bfr, acc[nt], 0, 0, 0);
        }
      }

#pragma unroll
      for (int r = 0; r < 4; ++r) {
        int grow = rowbase + lg * 4 + r;
        bool ok = grow < n;
        if (ok) {
#pragma unroll
          for (int nt = 0; nt < 4; ++nt)
            featb[(size_t)grow * HD + nt * 16 + lr] = f2bf(acc[nt][r]);
        }
        float pl[NH], pr[NH];
#pragma unroll
        for (int h = 0; h < NH; ++h) { pl[h] = acc[h][r] * al[h]; pr[h] = acc[h][r] * ar[h]; }
#pragma unroll
        for (int off = 1; off < 16; off <<= 1) {
#pragma unroll
          for (int h = 0; h < NH; ++h) {
            pl[h] += __shfl_xor(pl[h], off);
            pr[h] += __shfl_xor(pr[h], off);
          }
        }
        if (ok && lr == 0) {
          el4[grow] = make_float4(pl[0], pl[1], pl[2], pl[3]);
          er4[grow] = make_float4(pr[0], pr[1], pr[2], pr[3]);
        }
      }
    }
    return;
  }

  if (blockIdx.x >= ngemm + nchunks) {
    // ======== ee role: ee[t][h] = sum_e (edge_emb@fc_e)[t,h,e] * attn_e[h,e] ========
    if (t < 128) {
      for (int r = 0; r < 8; ++r) {
        float acc = 0.f;
#pragma unroll
        for (int k = 0; k < 32; ++k) acc = fmaf(edge_emb[r * 32 + k], fc_e_W[k * 128 + t], acc);
        sm.sef[r][t] = acc;
      }
    }
    __syncthreads();
    if (t < 32) {
      int r = t >> 2, h = t & 3;
      float acc = 0.f;
#pragma unroll
      for (int e2 = 0; e2 < 32; ++e2) acc += sm.sef[r][h * 32 + e2] * attn_e[h * 32 + e2];
      ee[r * NH + h] = acc;
    }
    return;
  }

  // ======== multisplit role: rec = src|et<<17|dlocal<<20 into fixed slabs ========
  const int base = (blockIdx.x - ngemm) * CHUNK;
  for (int i = t; i < nb; i += 512) sm.m.scnt[i] = 0;
  __syncthreads();
  unsigned pk[EPT], rc[EPT];
#pragma unroll
  for (int i = 0; i < EPT; ++i) {
    int e = base + i * 512 + t;
    pk[i] = 0xFFFFFFFFu;
    if (e < ne) {
      int d = dst[e];
      int bin = d >> 6;
      rc[i] = (unsigned)src[e] | ((unsigned)et[e] << 17) | ((unsigned)(d & 63) << 20);
      int slot = atomicAdd(&sm.m.scnt[bin], 1);
      pk[i] = ((unsigned)slot << 11) | (unsigned)bin;
    }
  }
  __syncthreads();
  int c[4], s = 0;
#pragma unroll
  for (int j = 0; j < 4; ++j) { int b = 4 * t + j; c[j] = (b < nb) ? sm.m.scnt[b] : 0; s += c[j]; }
  int inc = s;
#pragma unroll
  for (int off = 1; off < 64; off <<= 1) {
    int v = __shfl_up(inc, off);
    if (lane >= off) inc += v;
  }
  if (lane == 63) sm.m.wsm[wv] = inc;
  __syncthreads();
  if (t == 0) { int r = 0; for (int k = 0; k < 8; ++k) { sm.m.wbs[k] = r; r += sm.m.wsm[k]; } }
  __syncthreads();
  int ex = sm.m.wbs[wv] + inc - s;
#pragma unroll
  for (int j = 0; j < 4; ++j) {
    int b = 4 * t + j;
    if (b < nb) {
      sm.m.sbase[b] = (unsigned short)ex;
      if (c[j] > 0) {
        int raw = atomicAdd(&cntg[b], c[j]);
        sm.m.goff[b] = (unsigned short)(raw < SLAB ? raw : SLAB);
      }
    }
    ex += c[j];
  }
  __syncthreads();
#pragma unroll
  for (int i = 0; i < EPT; ++i) {
    if (pk[i] != 0xFFFFFFFFu) {
      int bin = (int)(pk[i] & 2047u);
      int slot = (int)(pk[i] >> 11);
      sm.m.sbuf[(int)sm.m.sbase[bin] + slot] = rc[i];
    }
  }
  __syncthreads();
  // copy-out to slabs: 8 record-lanes per bin, 64 bins per block-iteration
  const int sub = lane >> 3, rl = lane & 7;
  for (int b0 = wv * 8 + sub; b0 < nb; b0 += 64) {
    int cnt = sm.m.scnt[b0];
    if (cnt > 0) {
      int sb = (int)sm.m.sbase[b0];
      int go = (int)sm.m.goff[b0];
      int allowed = SLAB - go;                 // capacity clamp (overflow -> dropped, fallback)
      if (allowed > cnt) allowed = cnt;
      unsigned* gp = ebuf + (size_t)b0 * SLAB + go;
      for (int i2 = rl; i2 < allowed; i2 += 8)
        gp[i2] = sm.m.sbuf[sb + i2];
    }
  }
}

// ---- P2: per-bucket LDS counting sort (reg-cached, one atomic) + register-accum aggregation ----
__global__ __launch_bounds__(512) void k_sortagg(
    const unsigned* __restrict__ ebuf, const int* __restrict__ cntg,
    const float* __restrict__ el, const float4* __restrict__ er4,
    const float* __restrict__ eeg, const uint4* __restrict__ featq,
    const int* __restrict__ src, const int* __restrict__ dst, const int* __restrict__ et,
    float4* __restrict__ out4, int n, int ne)
{
  __shared__ unsigned sbuf[SBUFSZ];    // 8 KB
  __shared__ int cnt[BN];              // histogram
  __shared__ int sb[BN + 1];           // segment bases (bucket-local)
  __shared__ float s_er[BN][NH];       // 1 KB
  __shared__ float s_ee[32];
  const int t = threadIdx.x;
  const int node0 = blockIdx.x * BN;
  const int count = cntg[blockIdx.x];
  const int beg = blockIdx.x * SLAB;
  const int end = beg + count;
  for (int i = t; i < BN; i += 512) {
    cnt[i] = 0;
    int node = node0 + i;
    float4 v = (node < n) ? er4[node] : make_float4(0.f, 0.f, 0.f, 0.f);
    s_er[i][0] = v.x; s_er[i][1] = v.y; s_er[i][2] = v.z; s_er[i][3] = v.w;
  }
  if (t < 32) s_ee[t] = eeg[t];
  __syncthreads();

  const int lane = t & 63, wv = t >> 6;
  const int q = lane >> 3;      // 8 records in flight per wave
  const int l = lane & 7;       // dim octet: dims 8l..8l+7
  const int h = l >> 1;         // head for this lane's dims
  const bool sorted = (count <= SBUFSZ);

  if (sorted) {
    // pass 1: histogram; cache record + within-bin slot in registers
    unsigned rr_[SBUFSZ / 512], pk_[SBUFSZ / 512];
#pragma unroll
    for (int j = 0; j < SBUFSZ / 512; ++j) {
      int i = beg + j * 512 + t;
      pk_[j] = 0xFFFFFFFFu;
      if (i < end) {
        unsigned r = ebuf[i];
        rr_[j] = r;
        unsigned bin = r >> 20;
        unsigned slot = (unsigned)atomicAdd(&cnt[bin], 1);
        pk_[j] = (slot << 6) | bin;
      }
    }
    __syncthreads();
    // scan 64 bins with wave 0
    if (t < 64) {
      int cc = cnt[t];
      int inc = cc;
#pragma unroll
      for (int off = 1; off < 64; off <<= 1) {
        int v = __shfl_up(inc, off);
        if (lane >= off) inc += v;
      }
      int ex = inc - cc;
      sb[t] = ex;
      if (t == 63) sb[64] = ex + cc;
    }
    __syncthreads();
    // pass 2: place from registers (no atomics, no re-read)
#pragma unroll
    for (int j = 0; j < SBUFSZ / 512; ++j) {
      if (pk_[j] != 0xFFFFFFFFu)
        sbuf[sb[pk_[j] & 63u] + (int)(pk_[j] >> 6)] = rr_[j];
    }
    __syncthreads();
  }

  // aggregation: wave wv owns dsts [wv*8, wv*8+8)
  for (int ld = wv * 8; ld < wv * 8 + 8; ++ld) {
    float erh = s_er[ld][h];
    float a0 = 0.f, a1 = 0.f, a2 = 0.f, a3 = 0.f;
    float a4 = 0.f, a5 = 0.f, a6 = 0.f, a7 = 0.f, den = 0.f;
    if (sorted) {
      const int s0 = sb[ld], s1 = sb[ld + 1];
      for (int i = s0 + q; i < s1; i += 8) {
        unsigned r = sbuf[i];
        int s  = (int)(r & 0x1FFFFu);
        int tt = (int)((r >> 17) & 7u);
        float sv = el[s * NH + h] + erh + s_ee[tt * NH + h];
        sv = sv > 0.f ? sv : NEG_SLOPE * sv;
        float p = __expf(sv);
        den += p;
        uint4 u = featq[(size_t)s * 8 + l];
        a0 = fmaf(p, __uint_as_float(u.x << 16), a0);
        a1 = fmaf(p, __uint_as_float(u.x & 0xFFFF0000u), a1);
        a2 = fmaf(p, __uint_as_float(u.y << 16), a2);
        a3 = fmaf(p, __uint_as_float(u.y & 0xFFFF0000u), a3);
        a4 = fmaf(p, __uint_as_float(u.z << 16), a4);
        a5 = fmaf(p, __uint_as_float(u.z & 0xFFFF0000u), a5);
        a6 = fmaf(p, __uint_as_float(u.w << 16), a6);
        a7 = fmaf(p, __uint_as_float(u.w & 0xFFFF0000u), a7);
      }
    } else {
      // fallback (statistically never): filtered rescan of the raw edge list
      int node = node0 + ld;
      for (int i = q; i < ne; i += 8) {
        if (dst[i] != node) continue;
        int s  = src[i];
        int tt = et[i];
        float sv = el[s * NH + h] + erh + s_ee[tt * NH + h];
        sv = sv > 0.f ? sv : NEG_SLOPE * sv;
        float p = __expf(sv);
        den += p;
        uint4 u = featq[(size_t)s * 8 + l];
        a0 = fmaf(p, __uint_as_float(u.x << 16), a0);
        a1 = fmaf(p, __uint_as_float(u.x & 0xFFFF0000u), a1);
        a2 = fmaf(p, __uint_as_float(u.y << 16), a2);
        a3 = fmaf(p, __uint_as_float(u.y & 0xFFFF0000u), a3);
        a4 = fmaf(p, __uint_as_float(u.z << 16), a4);
        a5 = fmaf(p, __uint_as_float(u.z & 0xFFFF0000u), a5);
        a6 = fmaf(p, __uint_as_float(u.w << 16), a6);
        a7 = fmaf(p, __uint_as_float(u.w & 0xFFFF0000u), a7);
      }
    }
#pragma unroll
    for (int off = 8; off <= 32; off <<= 1) {
      den += __shfl_xor(den, off);
      a0 += __shfl_xor(a0, off); a1 += __shfl_xor(a1, off);
      a2 += __shfl_xor(a2, off); a3 += __shfl_xor(a3, off);
      a4 += __shfl_xor(a4, off); a5 += __shfl_xor(a5, off);
      a6 += __shfl_xor(a6, off); a7 += __shfl_xor(a7, off);
    }
    if (q == 0) {
      int node = node0 + ld;
      if (node < n) {
        float inv = den > 0.f ? 1.f / den : 0.f;
        float4* op = out4 + (size_t)node * 16 + l * 2;
        op[0] = make_float4(a0 * inv, a1 * inv, a2 * inv, a3 * inv);
        op[1] = make_float4(a4 * inv, a5 * inv, a6 * inv, a7 * inv);
      }
    }
  }
}

extern "C" void kernel_launch(void* const* d_in, const int* in_sizes, int n_in,
                              void* d_out, int out_size, void* d_ws, size_t ws_size,
                              hipStream_t stream)
{
  const float* x        = (const float*)d_in[0];
  const int*   src      = (const int*)d_in[1];
  const int*   dst      = (const int*)d_in[2];
  const int*   etype    = (const int*)d_in[3];
  const float* fcW      = (const float*)d_in[4];
  const float* fceW     = (const float*)d_in[5];
  const float* edge_emb = (const float*)d_in[6];
  const float* attn_l   = (const float*)d_in[7];
  const float* attn_r   = (const float*)d_in[8];
  const float* attn_e   = (const float*)d_in[9];
  float* out = (float*)d_out;

  const int n  = in_sizes[0] / IN_DIM;      // 100000
  const int ne = in_sizes[1];               // 1600000
  const int nb = (n + BN - 1) / BN;         // 1563 buckets
  const int nchunks = (ne + CHUNK - 1) / CHUNK;   // 391 multisplit blocks

  char* ws = (char*)d_ws;
  size_t off = 0;
  unsigned short* featb = (unsigned short*)(ws + off); off += (size_t)n * HD * sizeof(unsigned short);
  float* el    = (float*)(ws + off); off += (size_t)n * NH * sizeof(float);
  float* er    = (float*)(ws + off); off += (size_t)n * NH * sizeof(float);
  float* ee    = (float*)(ws + off); off += 256;
  int* cntg    = (int*)(ws + off);   off += NBMAX * sizeof(int);
  unsigned* ebuf = (unsigned*)(ws + off); off += (size_t)NBMAX * SLAB * sizeof(unsigned);

  hipMemsetAsync(cntg, 0, NBMAX * sizeof(int), stream);

  k_combo<<<NGEMM + nchunks + 1, 512, 0, stream>>>(
      x, fcW, attn_l, attn_r, featb, (float4*)el, (float4*)er,
      src, dst, etype, cntg, ebuf, edge_emb, fceW, attn_e, ee,
      n, ne, nb, NGEMM, nchunks);
  k_sortagg<<<nb, 512, 0, stream>>>(ebuf, cntg, el, (const float4*)er, ee,
                                    (const uint4*)featb, src, dst, etype,
                                    (float4*)out, n, ne);
}

// Round 16
// 104.754 us; speedup vs baseline: 8.1314x; 1.0957x over previous
//
#include <hip/hip_runtime.h>

#define NH 4
#define HD 64
#define IN_DIM 128
#define NEG_SLOPE 0.2f
#define BN 256          // dst nodes per bucket
#define NBMAX 512       // max buckets (n <= 131072)
#define SLAB 5120       // records per bucket slab (mean 4092, sigma ~64 -> +16 sigma)
#define CHUNK 4096      // edges per multisplit block
#define EPT (CHUNK/512) // edges per thread in multisplit (512-thread blocks)
#define SBUFSZ SLAB     // sortagg sort capacity
#define NGEMM 391       // GEMM role blocks in k_combo

typedef short bf8 __attribute__((ext_vector_type(8)));   // 8 bf16 in 4 VGPRs
typedef float f4  __attribute__((ext_vector_type(4)));

__device__ inline unsigned short f2bf(float f) {   // RNE fp32 -> bf16
  unsigned u = __float_as_uint(f);
  u += 0x7FFFu + ((u >> 16) & 1u);
  return (unsigned short)(u >> 16);
}

// ---- P1: combined dispatch. Roles by blockIdx:
//   [0, ngemm)            : MFMA projection feat/el/er
//   [ngemm, ngemm+nchunks): multisplit into fixed-capacity 256-node bucket slabs
//   ngemm+nchunks         : tiny ee[t][h] table
__global__ __launch_bounds__(512) void k_combo(
    const float* __restrict__ x, const float* __restrict__ fcW,
    const float* __restrict__ attn_l, const float* __restrict__ attn_r,
    unsigned short* __restrict__ featb, float4* __restrict__ el4, float4* __restrict__ er4,
    const int* __restrict__ src, const int* __restrict__ dst, const int* __restrict__ et,
    int* __restrict__ cntg, unsigned* __restrict__ ebuf,
    const float* __restrict__ edge_emb, const float* __restrict__ fc_e_W,
    const float* __restrict__ attn_e, float* __restrict__ ee,
    int n, int ne, int nb, int ngemm, int nchunks)
{
  __shared__ union {
    struct {
      int scnt[NBMAX];                 // 2 KB
      unsigned short sbase[NBMAX];     // 1 KB
      unsigned short goff[NBMAX];      // 1 KB (slab offset, clamped <= SLAB)
      unsigned sbuf[CHUNK];            // 16 KB
      int wsm[8], wbs[8];
    } m;
    unsigned short wt[HD][IN_DIM + 8]; // 17.4 KB (GEMM role)
    float sef[8][128];                 // 4 KB (ee role)
  } sm;

  const int t = threadIdx.x;
  const int lane = t & 63, wv = t >> 6;

  if (blockIdx.x < ngemm) {
    // ======== GEMM role: feat(bf16) = x @ fc_W + el/er; 8 waves = 128 rows/iter ========
    for (int idx = t; idx < IN_DIM * HD; idx += 512) {
      int k = idx >> 6, j = idx & 63;
      sm.wt[j][k] = f2bf(fcW[idx]);
    }
    __syncthreads();

    const int lr = lane & 15;
    const int lg = lane >> 4;
    float al[NH], ar[NH];
#pragma unroll
    for (int h = 0; h < NH; ++h) { al[h] = attn_l[h * 16 + lr]; ar[h] = attn_r[h * 16 + lr]; }

    const int ntp = (n + 127) >> 7;     // tile pairs of 128 rows
    for (int tp = blockIdx.x; tp < ntp; tp += ngemm) {
      const int rowbase = tp * 128 + wv * 16;
      int arow = rowbase + lr;
      if (arow >= n) arow = n - 1;                   // clamp; stores predicated
      const float* xp = x + (size_t)arow * IN_DIM + lg * 8;

      f4 acc[4] = {};                                // one per n-tile (= head)
#pragma unroll
      for (int kc = 0; kc < 4; ++kc) {
        float4 a0 = *(const float4*)(xp + kc * 32);
        float4 a1 = *(const float4*)(xp + kc * 32 + 4);
        bf8 af;
        af[0] = (short)f2bf(a0.x); af[1] = (short)f2bf(a0.y);
        af[2] = (short)f2bf(a0.z); af[3] = (short)f2bf(a0.w);
        af[4] = (short)f2bf(a1.x); af[5] = (short)f2bf(a1.y);
        af[6] = (short)f2bf(a1.z); af[7] = (short)f2bf(a1.w);
#pragma unroll
        for (int nt = 0; nt < 4; ++nt) {
          bf8 bfr = *(const bf8*)&sm.wt[nt * 16 + lr][kc * 32 + lg * 8];
          acc[nt] = __builtin_amdgcn_mfma_f32_16x16x32_bf16(af, bfr, acc[nt], 0, 0, 0);
        }
      }

#pragma unroll
      for (int r = 0; r < 4; ++r) {
        int grow = rowbase + lg * 4 + r;
        bool ok = grow < n;
        if (ok) {
#pragma unroll
          for (int nt = 0; nt < 4; ++nt)
            featb[(size_t)grow * HD + nt * 16 + lr] = f2bf(acc[nt][r]);
        }
        float pl[NH], pr[NH];
#pragma unroll
        for (int h = 0; h < NH; ++h) { pl[h] = acc[h][r] * al[h]; pr[h] = acc[h][r] * ar[h]; }
#pragma unroll
        for (int off = 1; off < 16; off <<= 1) {
#pragma unroll
          for (int h = 0; h < NH; ++h) {
            pl[h] += __shfl_xor(pl[h], off);
            pr[h] += __shfl_xor(pr[h], off);
          }
        }
        if (ok && lr == 0) {
          el4[grow] = make_float4(pl[0], pl[1], pl[2], pl[3]);
          er4[grow] = make_float4(pr[0], pr[1], pr[2], pr[3]);
        }
      }
    }
    return;
  }

  if (blockIdx.x >= ngemm + nchunks) {
    // ======== ee role ========
    if (t < 128) {
      for (int r = 0; r < 8; ++r) {
        float acc = 0.f;
#pragma unroll
        for (int k = 0; k < 32; ++k) acc = fmaf(edge_emb[r * 32 + k], fc_e_W[k * 128 + t], acc);
        sm.sef[r][t] = acc;
      }
    }
    __syncthreads();
    if (t < 32) {
      int r = t >> 2, h = t & 3;
      float acc = 0.f;
#pragma unroll
      for (int e2 = 0; e2 < 32; ++e2) acc += sm.sef[r][h * 32 + e2] * attn_e[h * 32 + e2];
      ee[r * NH + h] = acc;
    }
    return;
  }

  // ======== multisplit role: rec = src|et<<17|dlocal<<20 into fixed slabs (bin = dst>>8) ========
  const int base = (blockIdx.x - ngemm) * CHUNK;
  for (int i = t; i < nb; i += 512) sm.m.scnt[i] = 0;
  __syncthreads();
  unsigned pk[EPT], rc[EPT];
#pragma unroll
  for (int i = 0; i < EPT; ++i) {
    int e = base + i * 512 + t;
    pk[i] = 0xFFFFFFFFu;
    if (e < ne) {
      int d = dst[e];
      int bin = d >> 8;
      rc[i] = (unsigned)src[e] | ((unsigned)et[e] << 17) | ((unsigned)(d & 255) << 20);
      int slot = atomicAdd(&sm.m.scnt[bin], 1);
      pk[i] = ((unsigned)slot << 9) | (unsigned)bin;
    }
  }
  __syncthreads();
  // scan: thread t owns bin t
  int c = (t < nb) ? sm.m.scnt[t] : 0;
  int inc = c;
#pragma unroll
  for (int off = 1; off < 64; off <<= 1) {
    int v = __shfl_up(inc, off);
    if (lane >= off) inc += v;
  }
  if (lane == 63) sm.m.wsm[wv] = inc;
  __syncthreads();
  if (t == 0) { int r = 0; for (int k = 0; k < 8; ++k) { sm.m.wbs[k] = r; r += sm.m.wsm[k]; } }
  __syncthreads();
  int ex = sm.m.wbs[wv] + inc - c;
  if (t < nb) {
    sm.m.sbase[t] = (unsigned short)ex;
    if (c > 0) {
      int raw = atomicAdd(&cntg[t], c);
      sm.m.goff[t] = (unsigned short)(raw < SLAB ? raw : SLAB);
    }
  }
  __syncthreads();
#pragma unroll
  for (int i = 0; i < EPT; ++i) {
    if (pk[i] != 0xFFFFFFFFu) {
      int bin = (int)(pk[i] & 511u);
      int slot = (int)(pk[i] >> 9);
      sm.m.sbuf[(int)sm.m.sbase[bin] + slot] = rc[i];
    }
  }
  __syncthreads();
  // copy-out to slabs: 8 record-lanes per bin, 64 bins per block-iteration
  const int sub = lane >> 3, rl = lane & 7;
  for (int b0 = wv * 8 + sub; b0 < nb; b0 += 64) {
    int cnt = sm.m.scnt[b0];
    if (cnt > 0) {
      int sb = (int)sm.m.sbase[b0];
      int go = (int)sm.m.goff[b0];
      int allowed = SLAB - go;                 // capacity clamp (overflow -> fallback)
      if (allowed > cnt) allowed = cnt;
      unsigned* gp = ebuf + (size_t)b0 * SLAB + go;
      for (int i2 = rl; i2 < allowed; i2 += 8)
        gp[i2] = sm.m.sbuf[sb + i2];
    }
  }
}

// ---- P2: per-256-node-bucket LDS counting sort + register-accum aggregation (1024 thr) ----
__global__ __launch_bounds__(1024) void k_sortagg(
    const unsigned* __restrict__ ebuf, const int* __restrict__ cntg,
    const float* __restrict__ el, const float4* __restrict__ er4,
    const float* __restrict__ eeg, const uint4* __restrict__ featq,
    const int* __restrict__ src, const int* __restrict__ dst, const int* __restrict__ et,
    float4* __restrict__ out4, int n, int ne)
{
  __shared__ unsigned sbuf[SBUFSZ];    // 20 KB
  __shared__ int cnt[BN];              // 1 KB histogram
  __shared__ int sb[BN + 1];           // segment bases (bucket-local)
  __shared__ float s_er[BN][NH];       // 4 KB
  __shared__ float s_ee[32];
  __shared__ int wsum[4];
  const int t = threadIdx.x;
  const int node0 = blockIdx.x * BN;
  const int count0 = cntg[blockIdx.x];
  const int count = count0 < SLAB ? count0 : SLAB;
  const int beg = blockIdx.x * SLAB;
  const int end = beg + count;
  for (int i = t; i < BN; i += 1024) {
    cnt[i] = 0;
    int node = node0 + i;
    float4 v = (node < n) ? er4[node] : make_float4(0.f, 0.f, 0.f, 0.f);
    s_er[i][0] = v.x; s_er[i][1] = v.y; s_er[i][2] = v.z; s_er[i][3] = v.w;
  }
  if (t < 32) s_ee[t] = eeg[t];
  __syncthreads();

  const int lane = t & 63, wv = t >> 6;    // 16 waves
  const int q = lane >> 3;      // 8 records in flight per wave
  const int l = lane & 7;       // dim octet: dims 8l..8l+7
  const int h = l >> 1;         // head for this lane's dims
  const bool sorted = (count0 <= SLAB);

  if (sorted) {
    // pass 1: histogram; cache record + within-bin slot in registers
    unsigned rr_[(SBUFSZ + 1023) / 1024], pk_[(SBUFSZ + 1023) / 1024];
#pragma unroll
    for (int j = 0; j < (SBUFSZ + 1023) / 1024; ++j) {
      int i = beg + j * 1024 + t;
      pk_[j] = 0xFFFFFFFFu;
      if (i < end) {
        unsigned r = ebuf[i];
        rr_[j] = r;
        unsigned bin = r >> 20;
        unsigned slot = (unsigned)atomicAdd(&cnt[bin], 1);
        pk_[j] = (slot << 8) | bin;
      }
    }
    __syncthreads();
    // scan 256 bins with waves 0-3
    int cc = 0, inc = 0;
    if (t < BN) {
      cc = cnt[t];
      inc = cc;
#pragma unroll
      for (int off = 1; off < 64; off <<= 1) {
        int v = __shfl_up(inc, off);
        if (lane >= off) inc += v;
      }
      if (lane == 63) wsum[wv] = inc;
    }
    __syncthreads();
    if (t < BN) {
      int base = 0;
#pragma unroll
      for (int k = 0; k < 4; ++k) if (k < wv) base += wsum[k];
      int ex = base + inc - cc;
      sb[t] = ex;
      if (t == BN - 1) sb[BN] = ex + cc;
    }
    __syncthreads();
    // pass 2: place from registers (no atomics, no re-read)
#pragma unroll
    for (int j = 0; j < (SBUFSZ + 1023) / 1024; ++j) {
      if (pk_[j] != 0xFFFFFFFFu)
        sbuf[sb[pk_[j] & 255u] + (int)(pk_[j] >> 8)] = rr_[j];
    }
    __syncthreads();
  }

  // aggregation: wave wv owns dsts [wv*16, wv*16+16)
  for (int ld = wv * 16; ld < wv * 16 + 16; ++ld) {
    float erh = s_er[ld][h];
    float a0 = 0.f, a1 = 0.f, a2 = 0.f, a3 = 0.f;
    float a4 = 0.f, a5 = 0.f, a6 = 0.f, a7 = 0.f, den = 0.f;
    if (sorted) {
      const int s0 = sb[ld], s1 = sb[ld + 1];
      for (int i = s0 + q; i < s1; i += 8) {
        unsigned r = sbuf[i];
        int s  = (int)(r & 0x1FFFFu);
        int tt = (int)((r >> 17) & 7u);
        float sv = el[s * NH + h] + erh + s_ee[tt * NH + h];
        sv = sv > 0.f ? sv : NEG_SLOPE * sv;
        float p = __expf(sv);
        den += p;
        uint4 u = featq[(size_t)s * 8 + l];
        a0 = fmaf(p, __uint_as_float(u.x << 16), a0);
        a1 = fmaf(p, __uint_as_float(u.x & 0xFFFF0000u), a1);
        a2 = fmaf(p, __uint_as_float(u.y << 16), a2);
        a3 = fmaf(p, __uint_as_float(u.y & 0xFFFF0000u), a3);
        a4 = fmaf(p, __uint_as_float(u.z << 16), a4);
        a5 = fmaf(p, __uint_as_float(u.z & 0xFFFF0000u), a5);
        a6 = fmaf(p, __uint_as_float(u.w << 16), a6);
        a7 = fmaf(p, __uint_as_float(u.w & 0xFFFF0000u), a7);
      }
    } else {
      // fallback (statistically never): filtered rescan of the raw edge list
      int node = node0 + ld;
      for (int i = q; i < ne; i += 8) {
        if (dst[i] != node) continue;
        int s  = src[i];
        int tt = et[i];
        float sv = el[s * NH + h] + erh + s_ee[tt * NH + h];
        sv = sv > 0.f ? sv : NEG_SLOPE * sv;
        float p = __expf(sv);
        den += p;
        uint4 u = featq[(size_t)s * 8 + l];
        a0 = fmaf(p, __uint_as_float(u.x << 16), a0);
        a1 = fmaf(p, __uint_as_float(u.x & 0xFFFF0000u), a1);
        a2 = fmaf(p, __uint_as_float(u.y << 16), a2);
        a3 = fmaf(p, __uint_as_float(u.y & 0xFFFF0000u), a3);
        a4 = fmaf(p, __uint_as_float(u.z << 16), a4);
        a5 = fmaf(p, __uint_as_float(u.z & 0xFFFF0000u), a5);
        a6 = fmaf(p, __uint_as_float(u.w << 16), a6);
        a7 = fmaf(p, __uint_as_float(u.w & 0xFFFF0000u), a7);
      }
    }
#pragma unroll
    for (int off = 8; off <= 32; off <<= 1) {
      den += __shfl_xor(den, off);
      a0 += __shfl_xor(a0, off); a1 += __shfl_xor(a1, off);
      a2 += __shfl_xor(a2, off); a3 += __shfl_xor(a3, off);
      a4 += __shfl_xor(a4, off); a5 += __shfl_xor(a5, off);
      a6 += __shfl_xor(a6, off); a7 += __shfl_xor(a7, off);
    }
    if (q == 0) {
      int node = node0 + ld;
      if (node < n) {
        float inv = den > 0.f ? 1.f / den : 0.f;
        float4* op = out4 + (size_t)node * 16 + l * 2;
        op[0] = make_float4(a0 * inv, a1 * inv, a2 * inv, a3 * inv);
        op[1] = make_float4(a4 * inv, a5 * inv, a6 * inv, a7 * inv);
      }
    }
  }
}

extern "C" void kernel_launch(void* const* d_in, const int* in_sizes, int n_in,
                              void* d_out, int out_size, void* d_ws, size_t ws_size,
                              hipStream_t stream)
{
  const float* x        = (const float*)d_in[0];
  const int*   src      = (const int*)d_in[1];
  const int*   dst      = (const int*)d_in[2];
  const int*   etype    = (const int*)d_in[3];
  const float* fcW      = (const float*)d_in[4];
  const float* fceW     = (const float*)d_in[5];
  const float* edge_emb = (const float*)d_in[6];
  const float* attn_l   = (const float*)d_in[7];
  const float* attn_r   = (const float*)d_in[8];
  const float* attn_e   = (const float*)d_in[9];
  float* out = (float*)d_out;

  const int n  = in_sizes[0] / IN_DIM;      // 100000
  const int ne = in_sizes[1];               // 1600000
  const int nb = (n + BN - 1) / BN;         // 391 buckets
  const int nchunks = (ne + CHUNK - 1) / CHUNK;   // 391 multisplit blocks

  char* ws = (char*)d_ws;
  size_t off = 0;
  unsigned short* featb = (unsigned short*)(ws + off); off += (size_t)n * HD * sizeof(unsigned short);
  float* el    = (float*)(ws + off); off += (size_t)n * NH * sizeof(float);
  float* er    = (float*)(ws + off); off += (size_t)n * NH * sizeof(float);
  float* ee    = (float*)(ws + off); off += 256;
  int* cntg    = (int*)(ws + off);   off += NBMAX * sizeof(int);
  unsigned* ebuf = (unsigned*)(ws + off); off += (size_t)NBMAX * SLAB * sizeof(unsigned);

  hipMemsetAsync(cntg, 0, NBMAX * sizeof(int), stream);

  k_combo<<<NGEMM + nchunks + 1, 512, 0, stream>>>(
      x, fcW, attn_l, attn_r, featb, (float4*)el, (float4*)er,
      src, dst, etype, cntg, ebuf, edge_emb, fceW, attn_e, ee,
      n, ne, nb, NGEMM, nchunks);
  k_sortagg<<<nb, 1024, 0, stream>>>(ebuf, cntg, el, (const float4*)er, ee,
                                     (const uint4*)featb, src, dst, etype,
                                     (float4*)out, n, ne);
}